// Round 7
// baseline (638.007 us; speedup 1.0000x reference)
//
#include <hip/hip_runtime.h>
#include <hip/hip_bf16.h>

typedef __attribute__((ext_vector_type(8))) short bf16x8;
typedef __attribute__((ext_vector_type(4))) float f32x4;
typedef unsigned short u16;
typedef unsigned int u32;

#define DI __device__ __forceinline__
#define MFMA16(a, b, c) __builtin_amdgcn_mfma_f32_16x16x32_bf16((a), (b), (c), 0, 0, 0)

constexpr int Hh = 128, Ww = 512;
constexpr int HW = 65536;                // H*W
constexpr long FULL = 16777216;          // B*C*H*W = 2*128*128*512
constexpr long HALF = 8388608;

// canonical staging (independent of harness dtype)
__device__ __align__(16) u16 g_buf[2 * FULL];   // 64 MB scratch
__device__ __align__(16) u16 g_w[950272];       // all weights, bf16
__device__ __align__(16) float g_bias[1216];    // all biases, f32
__device__ __align__(16) float g_fc[32768];     // SKN fc weights, f32
__device__ __align__(16) float g_pools[1024];
__device__ __align__(16) float g_gates[1536];
__device__ __align__(16) float g_ppart[524288]; // [ts2][b2][c128][blk1024] partial pools
__device__ int g_flag;                          // 1 = inputs are f32, 0 = bf16

// g_w offsets (u16 elements)
constexpr int EMB_L = 0, EMB_R = 8192, EMB_RV = 16384, HEAD = 24576, OUTL = 57344, BODY = 65536;
// g_bias offsets
constexpr int B_EMBL = 0, B_EMBR = 64, B_EMBRV = 128, B_OUTL = 192, B_HEAD = 320, B_B1 = 448, B_B2 = 832;
// g_fc offsets
constexpr int FC1A = 0, FC2A = 4096, FC1B = 16384, FC2B = 20480;

DI float b2f(u16 u) { union { u32 i; float f; } v; v.i = (u32)u << 16; return v.f; }
DI u16 f2b(float f) {
  union { float fl; u32 u; } v; v.fl = f;
  return (u16)((v.u + 0x7FFFu + ((v.u >> 16) & 1u)) >> 16);
}
DI float ldf(const void* p, long i, int f) {
  return f ? ((const float*)p)[i] : b2f(((const u16*)p)[i]);
}
DI bf16x8 ld8(const void* p) { return *reinterpret_cast<const bf16x8*>(p); }
DI void gload16(const u16* src, char* lds_dst) {
  __builtin_amdgcn_global_load_lds(
      (const __attribute__((address_space(1))) void*)src,
      (__attribute__((address_space(3))) void*)lds_dst, 16, 0, 0);
}

// ---------------- dtype detection
__global__ void k_detect(const void* left) {
  if (threadIdx.x != 0 || blockIdx.x != 0) return;
  const u16* pu = (const u16*)left;
  int okb = 0;
  for (int i = 0; i < 256; i++) {
    float x = b2f(pu[i]);
    float a = fabsf(x);
    if (x == 0.f || (a > 1e-8f && a < 1e4f)) okb++;
  }
  g_flag = (okb >= 230) ? 0 : 1;
}

// ---------------- pack ALL weights/biases to canonical buffers (flag-aware)
__global__ void k_pack(const void* w1, const void* w2, const void* embl, const void* embr,
                       const void* embrv, const void* outl, const void* head,
                       const void* embl_b, const void* embr_b, const void* embrv_b,
                       const void* outl_b, const void* head_b, const void* b1, const void* b2,
                       const void* f1a, const void* f2a, const void* f1b, const void* f2b_) {
  int f = g_flag;
  int i = blockIdx.x * 256 + threadIdx.x;
  int job = blockIdx.y;
  if (job == 0) {                 // body weights repack: wp[(blk*2+conv)*9+t][o][c]
    if (i >= 884736) return;
    int c = i & 127, o = (i >> 7) & 127;
    int rest = i >> 14;
    int t = rest % 9, bc = rest / 9;
    const void* src = (bc & 1) ? w2 : w1;
    int blk = bc >> 1;
    g_w[BODY + i] = f2b(ldf(src, (((long)(blk * 128 + o) * 128 + c)) * 9 + t, f));
  } else if (job == 1) {          // 1x1 weights (already [O][C] row-major)
    if (i >= 65536) return;
    float v;
    if (i < 8192) v = ldf(embl, i, f);
    else if (i < 16384) v = ldf(embr, i - 8192, f);
    else if (i < 24576) v = ldf(embrv, i - 16384, f);
    else if (i < 57344) v = ldf(head, i - 24576, f);
    else v = ldf(outl, i - 57344, f);
    g_w[i] = f2b(v);
  } else if (job == 2) {          // biases
    if (i >= 1216) return;
    float v;
    if (i < 64) v = ldf(embl_b, i, f);
    else if (i < 128) v = ldf(embr_b, i - 64, f);
    else if (i < 192) v = ldf(embrv_b, i - 128, f);
    else if (i < 320) v = ldf(outl_b, i - 192, f);
    else if (i < 448) v = ldf(head_b, i - 320, f);
    else if (i < 832) v = ldf(b1, i - 448, f);
    else v = ldf(b2, i - 832, f);
    g_bias[i] = v;
  } else {                        // fc weights
    if (i >= 32768) return;
    float v;
    if (i < 4096) v = ldf(f1a, i, f);
    else if (i < 16384) v = ldf(f2a, i - 4096, f);
    else if (i < 20480) v = ldf(f1b, i - 16384, f);
    else v = ldf(f2b_, i - 20480, f);
    g_fc[i] = v;
  }
}

// ---------------- NCHW -> NHWC transpose + bf16 canonicalization + pool partials
__global__ __launch_bounds__(256) void k_nchw2nhwc(const void* srcL, const void* srcR,
                                                   u16* __restrict__ dstL, u16* __restrict__ dstR) {
  __shared__ u16 tile[64][130];
  int f = g_flag;
  int w0 = blockIdx.x * 64;
  int h = blockIdx.y;
  int b = blockIdx.z & 1;
  int img = blockIdx.z >> 1;
  const void* src = img ? srcR : srcL;
  u16* dst = img ? dstR : dstL;
  int t = threadIdx.x;
  int wq = (t & 31) * 2, cb = t >> 5;
  for (int c0 = 0; c0 < 128; c0 += 8) {
    int c = c0 + cb;
    long base = (long)(b * 128 + c) * HW + h * Ww + w0 + wq;
    if (f) {
      float2 v = *reinterpret_cast<const float2*>((const float*)src + base);
      tile[wq][c] = f2b(v.x);
      tile[wq + 1][c] = f2b(v.y);
    } else {
      u32 v = *reinterpret_cast<const u32*>((const u16*)src + base);
      tile[wq][c] = (u16)v;
      tile[wq + 1][c] = (u16)(v >> 16);
    }
  }
  __syncthreads();
  int c = t & 127, wb = t >> 7;
  long obase = (long)b * HW + (long)h * Ww + w0;
  for (int w1i = 0; w1i < 64; w1i += 2) {
    int w = w1i + wb;
    dst[(obase + w) * 128 + c] = tile[w][c];
  }
  // SKN pool partials for left/right (sum over this block's 64 w at height h)
  if (t < 128) {
    float s = 0.f;
#pragma unroll
    for (int w = 0; w < 64; w++) s += b2f(tile[w][t]);
    g_ppart[((img * 2 + b) * 128 + t) * 1024 + (h * 8 + blockIdx.x)] = s;
  }
}

// ---------------- generic 1x1 conv as GEMM
template<int K, int N, bool RELU, bool NCHW_OUT>
__global__ __launch_bounds__(256) void k_gemm1x1(const u16* __restrict__ xt, const u16* __restrict__ w,
                                                 const float* __restrict__ bias, u16* __restrict__ out,
                                                 int wstride) {
  extern __shared__ __align__(16) char smem[];
  constexpr int SLOTS = (K * 2) / 16;
  constexpr int RB = K * 2;
  int t = threadIdx.x;
  long p0 = (long)blockIdx.x * 128;
  for (int u = t; u < 128 * SLOTS; u += 256) {
    int row = u / SLOTS, slot = u % SLOTS;
    int4 v = *reinterpret_cast<const int4*>(xt + (p0 + row) * K + slot * 8);
    *reinterpret_cast<int4*>(smem + (((u32)(row * RB + slot * 16)) ^ ((row & 7) << 4))) = v;
  }
  __syncthreads();
  int wid = t >> 6, lane = t & 63, l15 = lane & 15, l4 = lane >> 4;
  constexpr int WAVES_M = (N == 64) ? 4 : 2;
  constexpr int MF = (128 / WAVES_M) / 16;
  int wm = (N == 64) ? wid : (wid >> 1);
  int wn = (N == 64) ? 0 : (wid & 1);
  int prow0 = wm * (128 / WAVES_M);
  int ocol0 = wn * 64;
  f32x4 zz = {0.f, 0.f, 0.f, 0.f};
  f32x4 acc[MF][4];
#pragma unroll
  for (int m = 0; m < MF; m++)
#pragma unroll
    for (int n = 0; n < 4; n++) acc[m][n] = zz;
#pragma unroll
  for (int k0 = 0; k0 < K; k0 += 32) {
    bf16x8 a[MF], bw[4];
#pragma unroll
    for (int m = 0; m < MF; m++) {
      int row = prow0 + m * 16 + l15;
      a[m] = ld8(smem + (((u32)(row * RB + (k0 + l4 * 8) * 2)) ^ ((row & 7) << 4)));
    }
#pragma unroll
    for (int n = 0; n < 4; n++) {
      int o = ocol0 + n * 16 + l15;
      bw[n] = ld8(w + (long)o * wstride + k0 + l4 * 8);
    }
#pragma unroll
    for (int m = 0; m < MF; m++)
#pragma unroll
      for (int n = 0; n < 4; n++) acc[m][n] = MFMA16(a[m], bw[n], acc[m][n]);
  }
  if constexpr (!NCHW_OUT) {
#pragma unroll
    for (int m = 0; m < MF; m++)
#pragma unroll
      for (int n = 0; n < 4; n++) {
        int o = ocol0 + n * 16 + l15;
        float bb = bias[o];
#pragma unroll
        for (int r = 0; r < 4; r++) {
          long p = p0 + prow0 + m * 16 + l4 * 4 + r;
          float v = acc[m][n][r] + bb;
          if (RELU) v = fmaxf(v, 0.f);
          out[p * N + o] = f2b(v);
        }
      }
  } else {
    __syncthreads();
    u16* tb = reinterpret_cast<u16*>(smem) + wid * (64 * 66);
#pragma unroll
    for (int m = 0; m < MF; m++)
#pragma unroll
      for (int n = 0; n < 4; n++) {
        float bb = bias[ocol0 + n * 16 + l15];
#pragma unroll
        for (int r = 0; r < 4; r++) {
          int pl = m * 16 + l4 * 4 + r;
          float v = acc[m][n][r] + bb;
          if (RELU) v = fmaxf(v, 0.f);
          tb[(n * 16 + l15) * 66 + pl] = f2b(v);
        }
      }
    __syncthreads();
    int bq = (int)(p0 / HW);
    int rem = (int)(p0 % HW);
    int hq = rem / Ww, wq0 = rem % Ww;
    for (int o = 0; o < 64; o++) {
      out[((long)(bq * 128 + ocol0 + o)) * HW + hq * Ww + wq0 + prow0 + lane] = tb[o * 66 + lane];
    }
  }
}

// ---------------- head: relu(leftT @ Wh[:,:128]^T + rightT @ Wh[:,128:]^T + b), NHWC out
// out may alias rt (in-place safe: each block reads/writes only its own rows).
__global__ __launch_bounds__(256) void k_head(const u16* lt, const u16* rt,
                                              const u16* __restrict__ wh, const float* __restrict__ bh,
                                              u16* out) {
  extern __shared__ __align__(16) char smem[];
  int t = threadIdx.x;
  long p0 = (long)blockIdx.x * 128;
  for (int u = t; u < 2048; u += 256) {
    int row = u >> 4, slot = u & 15;
    u32 db = ((u32)(row * 256 + slot * 16)) ^ ((row & 7) << 4);
    *reinterpret_cast<int4*>(smem + db) = *reinterpret_cast<const int4*>(lt + (p0 + row) * 128 + slot * 8);
    *reinterpret_cast<int4*>(smem + 32768 + db) = *reinterpret_cast<const int4*>(rt + (p0 + row) * 128 + slot * 8);
  }
  __syncthreads();
  int wid = t >> 6, lane = t & 63, l15 = lane & 15, l4 = lane >> 4;
  int prow0 = (wid >> 1) * 64, ocol0 = (wid & 1) * 64;
  f32x4 zz = {0.f, 0.f, 0.f, 0.f};
  f32x4 acc[4][4];
#pragma unroll
  for (int m = 0; m < 4; m++)
#pragma unroll
    for (int n = 0; n < 4; n++) acc[m][n] = zz;
#pragma unroll
  for (int kk = 0; kk < 8; kk++) {
    int k0 = kk * 32;
    const char* sb = smem + ((kk >= 4) ? 32768 : 0);
    int kl = k0 & 127;
    bf16x8 a[4], bw[4];
#pragma unroll
    for (int m = 0; m < 4; m++) {
      int row = prow0 + m * 16 + l15;
      a[m] = ld8(sb + (((u32)(row * 256 + (kl + l4 * 8) * 2)) ^ ((row & 7) << 4)));
    }
#pragma unroll
    for (int n = 0; n < 4; n++) {
      int o = ocol0 + n * 16 + l15;
      bw[n] = ld8(wh + o * 256 + k0 + l4 * 8);
    }
#pragma unroll
    for (int m = 0; m < 4; m++)
#pragma unroll
      for (int n = 0; n < 4; n++) acc[m][n] = MFMA16(a[m], bw[n], acc[m][n]);
  }
  __syncthreads();
#pragma unroll
  for (int m = 0; m < 4; m++)
#pragma unroll
    for (int n = 0; n < 4; n++) {
      int o = ocol0 + n * 16 + l15;
      float bb = bh[o];
#pragma unroll
      for (int r = 0; r < 4; r++) {
        long p = p0 + prow0 + m * 16 + l4 * 4 + r;
        float v = fmaxf(acc[m][n][r] + bb, 0.f);
        out[p * 128 + o] = f2b(v);
      }
    }
}

// ---------------- windowed cross-attention
__global__ __launch_bounds__(256) void k_attn(const u16* __restrict__ qt, const u16* __restrict__ kt,
                                              const u16* __restrict__ vt, u16* __restrict__ outT) {
  extern __shared__ __align__(16) char smem[];
  int n = blockIdx.x, h = blockIdx.y, b = blockIdx.z;
  long rb = ((long)(b * Hh + h)) * Ww + n * 128;
  int t = threadIdx.x;
  for (int u = t; u < 1024; u += 256) {
    int row = u >> 3, slot = u & 7;
    u32 db = ((u32)(row * 128 + slot * 16)) ^ ((row & 7) << 4);
    *reinterpret_cast<int4*>(smem + db) = *reinterpret_cast<const int4*>(qt + (rb + row) * 64 + slot * 8);
    *reinterpret_cast<int4*>(smem + 16384 + db) = *reinterpret_cast<const int4*>(kt + (rb + row) * 64 + slot * 8);
  }
  __syncthreads();
  int wid = t >> 6, lane = t & 63, l15 = lane & 15, l4 = lane >> 4;
  int q0 = wid * 32;
  f32x4 zz = {0.f, 0.f, 0.f, 0.f};
  f32x4 sc[2][8];
#pragma unroll
  for (int m = 0; m < 2; m++)
#pragma unroll
    for (int nf = 0; nf < 8; nf++) sc[m][nf] = zz;
#pragma unroll
  for (int k0 = 0; k0 < 64; k0 += 32) {
    bf16x8 aq[2], bk[8];
#pragma unroll
    for (int m = 0; m < 2; m++) {
      int row = q0 + m * 16 + l15;
      aq[m] = ld8(smem + (((u32)(row * 128 + (k0 + l4 * 8) * 2)) ^ ((row & 7) << 4)));
    }
#pragma unroll
    for (int nf = 0; nf < 8; nf++) {
      int row = nf * 16 + l15;
      bk[nf] = ld8(smem + 16384 + (((u32)(row * 128 + (k0 + l4 * 8) * 2)) ^ ((row & 7) << 4)));
    }
#pragma unroll
    for (int m = 0; m < 2; m++)
#pragma unroll
      for (int nf = 0; nf < 8; nf++) sc[m][nf] = MFMA16(aq[m], bk[nf], sc[m][nf]);
  }
  float rsum[2][4];
#pragma unroll
  for (int m = 0; m < 2; m++) {
#pragma unroll
    for (int r = 0; r < 4; r++) {
      float mx = -3.0e38f;
#pragma unroll
      for (int nf = 0; nf < 8; nf++) mx = fmaxf(mx, sc[m][nf][r]);
      mx = fmaxf(mx, __shfl_xor(mx, 1));
      mx = fmaxf(mx, __shfl_xor(mx, 2));
      mx = fmaxf(mx, __shfl_xor(mx, 4));
      mx = fmaxf(mx, __shfl_xor(mx, 8));
      int ql = q0 + m * 16 + l4 * 4 + r;
      float ssum = 0.f;
#pragma unroll
      for (int nf = 0; nf < 8; nf++) {
        float e = __expf(sc[m][nf][r] - mx);
        ssum += e;
        int k = nf * 16 + l15;
        *reinterpret_cast<u16*>(smem + 32768 + (((u32)(ql * 256 + k * 2)) ^ ((ql & 7) << 4))) = f2b(e);
      }
      ssum += __shfl_xor(ssum, 1);
      ssum += __shfl_xor(ssum, 2);
      ssum += __shfl_xor(ssum, 4);
      ssum += __shfl_xor(ssum, 8);
      rsum[m][r] = ssum;
    }
  }
  __syncthreads();
  for (int u = t; u < 8192; u += 256) {
    int k = u >> 6, c = u & 63;
    u16 v = vt[(rb + k) * 64 + c];
    *reinterpret_cast<u16*>(smem + (((u32)(c * 256 + k * 2)) ^ ((c & 7) << 4))) = v;
  }
  __syncthreads();
  f32x4 ov[2][4];
#pragma unroll
  for (int m = 0; m < 2; m++)
#pragma unroll
    for (int nf = 0; nf < 4; nf++) ov[m][nf] = zz;
#pragma unroll
  for (int k0 = 0; k0 < 128; k0 += 32) {
    bf16x8 ap[2], bv[4];
#pragma unroll
    for (int m = 0; m < 2; m++) {
      int row = q0 + m * 16 + l15;
      ap[m] = ld8(smem + 32768 + (((u32)(row * 256 + (k0 + l4 * 8) * 2)) ^ ((row & 7) << 4)));
    }
#pragma unroll
    for (int nf = 0; nf < 4; nf++) {
      int c = nf * 16 + l15;
      bv[nf] = ld8(smem + (((u32)(c * 256 + (k0 + l4 * 8) * 2)) ^ ((c & 7) << 4)));
    }
#pragma unroll
    for (int m = 0; m < 2; m++)
#pragma unroll
      for (int nf = 0; nf < 4; nf++) ov[m][nf] = MFMA16(ap[m], bv[nf], ov[m][nf]);
  }
#pragma unroll
  for (int m = 0; m < 2; m++)
#pragma unroll
    for (int nf = 0; nf < 4; nf++)
#pragma unroll
      for (int r = 0; r < 4; r++) {
        int q = q0 + m * 16 + l4 * 4 + r;
        int c = nf * 16 + l15;
        outT[(rb + q) * 64 + c] = f2b(ov[m][nf][r] / rsum[m][r]);
      }
}

// ---------------- conv1x9: x-tile LDS-resident; 3-buffer depth-2 weight pipeline,
// counted vmcnt + raw s_barrier (never drain to 0 in main loop). K=32 per stage, 36 steps.
template<bool RELU, bool HASRES, bool NCHW_OUT>
__global__ __launch_bounds__(256) void k_conv1x9(const u16* __restrict__ xin, const u16* __restrict__ wp9,
                                                 const float* __restrict__ bias, const u16* __restrict__ res,
                                                 u16* __restrict__ out) {
  __shared__ __align__(16) char xs[34816];   // 136 rows x 256B, XOR-swizzled
  __shared__ __align__(16) char wbuf[24576]; // 3 x 8KB; each [128 o][64B] (K=32), slot-involution
  int w0 = blockIdx.x * 128;
  int h = blockIdx.y, b = blockIdx.z;
  long rowg = ((long)(b * Hh + h)) * Ww;
  int t = threadIdx.x;
  int wid = t >> 6;
  // stage(s,buf): B-tile for step s (tap=s>>2, kk=s&3) into wbuf[buf].
  // physical 16B slot sl holds logical slot sl^(o&3)  (involution, bank-spread).
  auto stage = [&](int s, int buf) {
    int tap = s >> 2, kk = s & 3;
    const u16* base = wp9 + tap * 16384 + kk * 32;
#pragma unroll
    for (int j = 0; j < 2; j++) {
      int u = j * 256 + t;           // 16B unit index 0..511
      int o = u >> 2, sl = u & 3;
      int l = sl ^ (o & 3);
      gload16(base + o * 128 + l * 8, wbuf + buf * 8192 + j * 4096 + wid * 1024);
    }
  };
  // x-tile staging (once)
  for (int u = t; u < 2176; u += 256) {
    int row = u >> 4, slot = u & 15;
    int wg = w0 - 4 + row;
    int4 v{0, 0, 0, 0};
    if (wg >= 0 && wg < Ww) v = *reinterpret_cast<const int4*>(xin + (rowg + wg) * 128 + slot * 8);
    *reinterpret_cast<int4*>(xs + (((u32)(row * 256 + slot * 16)) ^ ((row & 7) << 4))) = v;
  }
  stage(0, 0);
  stage(1, 1);
  asm volatile("s_waitcnt vmcnt(2) lgkmcnt(0)" ::: "memory");   // stage(0) landed; x-tile written
  __builtin_amdgcn_s_barrier();
  __builtin_amdgcn_sched_barrier(0);
  int lane = t & 63, l15 = lane & 15, l4 = lane >> 4;
  int p0w = (wid >> 1) * 64, o0w = (wid & 1) * 64;
  f32x4 zz = {0.f, 0.f, 0.f, 0.f};
  f32x4 acc[4][4];
#pragma unroll
  for (int m = 0; m < 4; m++)
#pragma unroll
    for (int n = 0; n < 4; n++) acc[m][n] = zz;
  int bcur = 0;
#pragma unroll 1
  for (int s = 0; s < 36; s++) {
    if (s < 34) {
      int b2i = bcur + 2; if (b2i >= 3) b2i -= 3;
      stage(s + 2, b2i);
    }
    int tap = s >> 2, kk = s & 3;
    const char* wb = wbuf + bcur * 8192;
    bf16x8 a[4], bw[4];
#pragma unroll
    for (int n = 0; n < 4; n++) {
      int o = o0w + n * 16 + l15;
      bw[n] = ld8(wb + o * 64 + ((l4 ^ (o & 3)) * 16));
    }
#pragma unroll
    for (int m = 0; m < 4; m++) {
      int row = p0w + m * 16 + l15 + tap;
      a[m] = ld8(xs + (((u32)(row * 256 + kk * 64 + l4 * 16)) ^ ((row & 7) << 4)));
    }
#pragma unroll
    for (int m = 0; m < 4; m++)
#pragma unroll
      for (int n = 0; n < 4; n++) acc[m][n] = MFMA16(a[m], bw[n], acc[m][n]);
    // ensure stage(s+1) landed (own loads) before collective barrier; keep stage(s+2) in flight
    if (s < 34) asm volatile("s_waitcnt vmcnt(2)" ::: "memory");
    else        asm volatile("s_waitcnt vmcnt(0)" ::: "memory");
    __builtin_amdgcn_s_barrier();
    __builtin_amdgcn_sched_barrier(0);
    bcur = bcur + 1; if (bcur >= 3) bcur -= 3;
  }
  float bb[4];
#pragma unroll
  for (int n = 0; n < 4; n++) bb[n] = bias[o0w + n * 16 + l15];
  if constexpr (!NCHW_OUT) {
#pragma unroll
    for (int m = 0; m < 4; m++)
#pragma unroll
      for (int n = 0; n < 4; n++) {
        int o = o0w + n * 16 + l15;
#pragma unroll
        for (int r = 0; r < 4; r++) {
          int p = w0 + p0w + m * 16 + l4 * 4 + r;
          float v = acc[m][n][r] + bb[n];
          if (RELU) v = fmaxf(v, 0.f);
          if (HASRES) v += b2f(res[(rowg + p) * 128 + o]);
          out[(rowg + p) * 128 + o] = f2b(v);
        }
      }
  } else {
    u16* tb = reinterpret_cast<u16*>(xs) + wid * (64 * 66);
#pragma unroll
    for (int m = 0; m < 4; m++)
#pragma unroll
      for (int n = 0; n < 4; n++) {
        int o = o0w + n * 16 + l15;
#pragma unroll
        for (int r = 0; r < 4; r++) {
          int pl = m * 16 + l4 * 4 + r;
          int p = w0 + p0w + pl;
          float v = acc[m][n][r] + bb[n];
          if (RELU) v = fmaxf(v, 0.f);
          if (HASRES) v += b2f(res[(rowg + p) * 128 + o]);
          tb[(n * 16 + l15) * 66 + pl] = f2b(v);
        }
      }
    __syncthreads();
    for (int o = 0; o < 64; o++) {
      out[((long)(b * 128 + o0w + o)) * HW + h * Ww + w0 + p0w + lane] = tb[o * 66 + lane];
    }
  }
}

// ---------------- pools: ts 0/1 reduce transpose partials; ts 2/3 scan lfw/mixed (bf16 NCHW)
__global__ __launch_bounds__(256) void k_pool(const u16* __restrict__ lfw, const u16* __restrict__ mixed) {
  int c = blockIdx.x, b = blockIdx.y, ts = blockIdx.z;
  float s = 0.f;
  if (ts < 2) {
    const float* pp = g_ppart + ((ts * 2 + b) * 128 + c) * 1024;
    for (int i = threadIdx.x; i < 1024; i += 256) s += pp[i];
  } else {
    long base = ((long)(b * 128 + c)) * HW;
    const u16* pu = (ts == 2) ? lfw + base : mixed + base;
    for (int i = threadIdx.x * 8; i < HW; i += 2048) {
      union { int4 v; u16 u[8]; } x;
      x.v = *reinterpret_cast<const int4*>(pu + i);
#pragma unroll
      for (int j = 0; j < 8; j++) s += b2f(x.u[j]);
    }
  }
#pragma unroll
  for (int m = 1; m < 64; m <<= 1) s += __shfl_xor(s, m);
  __shared__ float red[4];
  if ((threadIdx.x & 63) == 0) red[threadIdx.x >> 6] = s;
  __syncthreads();
  if (threadIdx.x == 0)
    g_pools[(ts * 2 + b) * 128 + c] = (red[0] + red[1] + red[2] + red[3]) * (1.f / HW);
}

// ---------------- SKN gate MLP + branch softmax (tiny)
__global__ void k_gate() {
  __shared__ float sv[128], zv[32];
  int b = blockIdx.x, s = blockIdx.y;
  int t = threadIdx.x;
  sv[t] = g_pools[(s * 2 + b) * 128 + t] + g_pools[(4 + b) * 128 + t] + g_pools[(6 + b) * 128 + t];
  __syncthreads();
  const float* fc1 = g_fc + (s ? FC1B : FC1A);
  const float* fc2 = g_fc + (s ? FC2B : FC2A);
  if (t < 32) {
    float z = 0.f;
    for (int c = 0; c < 128; c++) z += fc1[t * 128 + c] * sv[c];
    zv[t] = (z > 0.f) ? z : 0.01f * z;
  }
  __syncthreads();
  float ab[3];
#pragma unroll
  for (int i = 0; i < 3; i++) {
    float a = 0.f;
    for (int j = 0; j < 32; j++) a += fc2[(i * 128 + t) * 32 + j] * zv[j];
    ab[i] = a;
  }
  float mx = fmaxf(ab[0], fmaxf(ab[1], ab[2]));
  float e0 = __expf(ab[0] - mx), e1 = __expf(ab[1] - mx), e2 = __expf(ab[2] - mx);
  float inv = 1.f / (e0 + e1 + e2);
  g_gates[((s * 2 + b) * 3 + 0) * 128 + t] = e0 * inv;
  g_gates[((s * 2 + b) * 3 + 1) * 128 + t] = e1 * inv;
  g_gates[((s * 2 + b) * 3 + 2) * 128 + t] = e2 * inv;
}

// ---------------- final weighted sums -> d_out (flag dtype)
__global__ __launch_bounds__(256) void k_skn_out(const void* left, const void* right,
                                                 const u16* __restrict__ lfw, const u16* __restrict__ mixed,
                                                 void* doutv) {
  int chunk = blockIdx.x, c = blockIdx.y, b = blockIdx.z;
  int f = g_flag;
  const float* g1 = g_gates + (b * 3) * 128 + c;
  const float* g2 = g_gates + ((2 + b) * 3) * 128 + c;
  float a10 = g1[0], a11 = g1[128], a12 = g1[256];
  float a20 = g2[0], a21 = g2[128], a22 = g2[256];
  long off = ((long)(b * 128 + c)) * HW + chunk * 2048 + threadIdx.x * 8;
  float xl[8], xr[8];
  if (f) {
    const float* L = (const float*)left + off;
    const float* R = (const float*)right + off;
    float4 a0 = *reinterpret_cast<const float4*>(L);
    float4 a1 = *reinterpret_cast<const float4*>(L + 4);
    float4 r0 = *reinterpret_cast<const float4*>(R);
    float4 r1 = *reinterpret_cast<const float4*>(R + 4);
    xl[0]=a0.x; xl[1]=a0.y; xl[2]=a0.z; xl[3]=a0.w; xl[4]=a1.x; xl[5]=a1.y; xl[6]=a1.z; xl[7]=a1.w;
    xr[0]=r0.x; xr[1]=r0.y; xr[2]=r0.z; xr[3]=r0.w; xr[4]=r1.x; xr[5]=r1.y; xr[6]=r1.z; xr[7]=r1.w;
  } else {
    union { int4 v; u16 u[8]; } a, r;
    a.v = *reinterpret_cast<const int4*>((const u16*)left + off);
    r.v = *reinterpret_cast<const int4*>((const u16*)right + off);
#pragma unroll
    for (int j = 0; j < 8; j++) { xl[j] = b2f(a.u[j]); xr[j] = b2f(r.u[j]); }
  }
  union { int4 v; u16 u[8]; } vw, vm;
  vw.v = *reinterpret_cast<const int4*>(lfw + off);
  vm.v = *reinterpret_cast<const int4*>(mixed + off);
  float ol[8], orr[8];
#pragma unroll
  for (int j = 0; j < 8; j++) {
    float fw = b2f(vw.u[j]), fm = b2f(vm.u[j]);
    ol[j] = a10 * xl[j] + a11 * fw + a12 * fm;
    orr[j] = a20 * xr[j] + a21 * fw + a22 * fm;
  }
  if (f) {
    float* fo = (float*)doutv;
    *reinterpret_cast<float4*>(fo + off) = make_float4(ol[0], ol[1], ol[2], ol[3]);
    *reinterpret_cast<float4*>(fo + off + 4) = make_float4(ol[4], ol[5], ol[6], ol[7]);
    *reinterpret_cast<float4*>(fo + FULL + off) = make_float4(orr[0], orr[1], orr[2], orr[3]);
    *reinterpret_cast<float4*>(fo + FULL + off + 4) = make_float4(orr[4], orr[5], orr[6], orr[7]);
  } else {
    u16* bo = (u16*)doutv;
    union { int4 v; u16 u[8]; } o1, o2;
#pragma unroll
    for (int j = 0; j < 8; j++) { o1.u[j] = f2b(ol[j]); o2.u[j] = f2b(orr[j]); }
    *reinterpret_cast<int4*>(bo + off) = o1.v;
    *reinterpret_cast<int4*>(bo + FULL + off) = o2.v;
  }
}

extern "C" void kernel_launch(void* const* d_in, const int* in_sizes, int n_in,
                              void* d_out, int out_size, void* d_ws, size_t ws_size,
                              hipStream_t stream) {
  (void)in_sizes; (void)n_in; (void)out_size; (void)d_ws; (void)ws_size;
  const void* left    = d_in[0];
  const void* right   = d_in[1];

  u16* gbuf = nullptr;
  (void)hipGetSymbolAddress((void**)&gbuf, HIP_SYMBOL(g_buf));
  u16* gw = nullptr;
  (void)hipGetSymbolAddress((void**)&gw, HIP_SYMBOL(g_w));
  float* gbias = nullptr;
  (void)hipGetSymbolAddress((void**)&gbias, HIP_SYMBOL(g_bias));

  // scratch plan (no D2D copies; end-state lfw/mixed in g_buf, d_out free before k_skn_out):
  u16* du = (u16*)d_out;
  u16* leftT   = du;                    // [0, FULL)        dead after k_head
  u16* rA      = du;                    // [0, FULL)        conv ping (after leftT dead)
  u16* rightT  = du + FULL;             // [FULL, 2FULL)    dead after k_head (head emits in-place)
  u16* xG      = du + FULL;             // [FULL, 2FULL)    head output / conv pong
  u16* QT      = gbuf;                  // [0, HALF)        dead after attn
  u16* KT      = gbuf + HALF;           // [HALF, FULL)     dead after attn
  u16* VrT     = gbuf + FULL;           // [FULL, 1.5FULL)  dead after attn
  u16* warpedT = gbuf + FULL + HALF;    // [1.5FULL, 2FULL) dead after out_l
  u16* lfw     = gbuf;                  // [0, FULL)        NCHW, lives to end (QT/KT dead)
  u16* mixed   = gbuf + FULL;           // [FULL, 2FULL)    NCHW, lives to end (VrT/warped dead)

  k_detect<<<dim3(1), dim3(64), 0, stream>>>(left);
  k_pack<<<dim3(3456, 4), dim3(256), 0, stream>>>(
      d_in[14], d_in[16], d_in[2], d_in[4], d_in[8], d_in[10], d_in[12],
      d_in[3], d_in[5], d_in[9], d_in[11], d_in[13], d_in[15], d_in[17],
      d_in[18], d_in[19], d_in[20], d_in[21]);
  k_nchw2nhwc<<<dim3(8, 128, 4), dim3(256), 0, stream>>>(left, right, leftT, rightT);
  k_gemm1x1<128, 64, false, false><<<dim3(1024), dim3(256), 32768, stream>>>(leftT, gw + EMB_L, gbias + B_EMBL, QT, 128);
  k_gemm1x1<128, 64, false, false><<<dim3(1024), dim3(256), 32768, stream>>>(rightT, gw + EMB_R, gbias + B_EMBR, KT, 128);
  k_gemm1x1<128, 64, false, false><<<dim3(1024), dim3(256), 32768, stream>>>(rightT, gw + EMB_RV, gbias + B_EMBRV, VrT, 128);
  k_head<<<dim3(1024), dim3(256), 65536, stream>>>(leftT, rightT, gw + HEAD, gbias + B_HEAD, xG);  // in-place over rightT
  k_attn<<<dim3(4, 128, 2), dim3(256), 65536, stream>>>(QT, KT, VrT, warpedT);          // QT,KT,VrT dead
  k_gemm1x1<64, 128, true, true><<<dim3(1024), dim3(256), 33792, stream>>>(warpedT, gw + OUTL, gbias + B_OUTL, lfw, 64);
  for (int i = 0; i < 3; i++) {
    k_conv1x9<true, false, false><<<dim3(4, 128, 2), dim3(256), 0, stream>>>(
        xG, gw + BODY + (long)(i * 2 + 0) * 9 * 16384, gbias + B_B1 + i * 128, nullptr, rA);
    if (i < 2)
      k_conv1x9<false, true, false><<<dim3(4, 128, 2), dim3(256), 0, stream>>>(
          rA, gw + BODY + (long)(i * 2 + 1) * 9 * 16384, gbias + B_B2 + i * 128, xG, xG);
    else
      k_conv1x9<false, true, true><<<dim3(4, 128, 2), dim3(256), 0, stream>>>(
          rA, gw + BODY + (long)(i * 2 + 1) * 9 * 16384, gbias + B_B2 + i * 128, xG, mixed);
  }
  k_pool<<<dim3(128, 2, 4), dim3(256), 0, stream>>>(lfw, mixed);
  k_gate<<<dim3(2, 2), dim3(128), 0, stream>>>();
  k_skn_out<<<dim3(32, 128, 2), dim3(256), 0, stream>>>(left, right, lfw, mixed, d_out);
}

// Round 8
// 590.798 us; speedup vs baseline: 1.0799x; 1.0799x over previous
//
#include <hip/hip_runtime.h>
#include <hip/hip_bf16.h>

typedef __attribute__((ext_vector_type(8))) short bf16x8;
typedef __attribute__((ext_vector_type(4))) float f32x4;
typedef unsigned short u16;
typedef unsigned int u32;

#define DI __device__ __forceinline__
#define MFMA16(a, b, c) __builtin_amdgcn_mfma_f32_16x16x32_bf16((a), (b), (c), 0, 0, 0)

constexpr int Hh = 128, Ww = 512;
constexpr int HW = 65536;                // H*W
constexpr long FULL = 16777216;          // B*C*H*W = 2*128*128*512
constexpr long HALF = 8388608;

// canonical staging (independent of harness dtype)
__device__ __align__(16) u16 g_buf[2 * FULL];   // 64 MB scratch
__device__ __align__(16) u16 g_w[950272];       // all weights, bf16
__device__ __align__(16) float g_bias[1216];    // all biases, f32
__device__ __align__(16) float g_fc[32768];     // SKN fc weights, f32
__device__ __align__(16) float g_pools[1024];
__device__ __align__(16) float g_gates[1536];
__device__ __align__(16) float g_ppart[524288]; // [ts2][b2][c128][blk1024] partial pools
__device__ int g_flag;                          // 1 = inputs are f32, 0 = bf16

// g_w offsets (u16 elements)
constexpr int EMB_L = 0, EMB_R = 8192, EMB_RV = 16384, HEAD = 24576, OUTL = 57344, BODY = 65536;
// g_bias offsets
constexpr int B_EMBL = 0, B_EMBR = 64, B_EMBRV = 128, B_OUTL = 192, B_HEAD = 320, B_B1 = 448, B_B2 = 832;
// g_fc offsets
constexpr int FC1A = 0, FC2A = 4096, FC1B = 16384, FC2B = 20480;

DI float b2f(u16 u) { union { u32 i; float f; } v; v.i = (u32)u << 16; return v.f; }
DI u16 f2b(float f) {
  union { float fl; u32 u; } v; v.fl = f;
  return (u16)((v.u + 0x7FFFu + ((v.u >> 16) & 1u)) >> 16);
}
DI float ldf(const void* p, long i, int f) {
  return f ? ((const float*)p)[i] : b2f(((const u16*)p)[i]);
}
DI bf16x8 ld8(const void* p) { return *reinterpret_cast<const bf16x8*>(p); }
DI void gload16(const u16* src, char* lds_dst) {
  __builtin_amdgcn_global_load_lds(
      (const __attribute__((address_space(1))) void*)src,
      (__attribute__((address_space(3))) void*)lds_dst, 16, 0, 0);
}

// ---------------- dtype detection
__global__ void k_detect(const void* left) {
  if (threadIdx.x != 0 || blockIdx.x != 0) return;
  const u16* pu = (const u16*)left;
  int okb = 0;
  for (int i = 0; i < 256; i++) {
    float x = b2f(pu[i]);
    float a = fabsf(x);
    if (x == 0.f || (a > 1e-8f && a < 1e4f)) okb++;
  }
  g_flag = (okb >= 230) ? 0 : 1;
}

// ---------------- pack ALL weights/biases to canonical buffers (flag-aware)
__global__ void k_pack(const void* w1, const void* w2, const void* embl, const void* embr,
                       const void* embrv, const void* outl, const void* head,
                       const void* embl_b, const void* embr_b, const void* embrv_b,
                       const void* outl_b, const void* head_b, const void* b1, const void* b2,
                       const void* f1a, const void* f2a, const void* f1b, const void* f2b_) {
  int f = g_flag;
  int i = blockIdx.x * 256 + threadIdx.x;
  int job = blockIdx.y;
  if (job == 0) {                 // body weights repack: wp[(blk*2+conv)*9+t][o][c]
    if (i >= 884736) return;
    int c = i & 127, o = (i >> 7) & 127;
    int rest = i >> 14;
    int t = rest % 9, bc = rest / 9;
    const void* src = (bc & 1) ? w2 : w1;
    int blk = bc >> 1;
    g_w[BODY + i] = f2b(ldf(src, (((long)(blk * 128 + o) * 128 + c)) * 9 + t, f));
  } else if (job == 1) {          // 1x1 weights (already [O][C] row-major)
    if (i >= 65536) return;
    float v;
    if (i < 8192) v = ldf(embl, i, f);
    else if (i < 16384) v = ldf(embr, i - 8192, f);
    else if (i < 24576) v = ldf(embrv, i - 16384, f);
    else if (i < 57344) v = ldf(head, i - 24576, f);
    else v = ldf(outl, i - 57344, f);
    g_w[i] = f2b(v);
  } else if (job == 2) {          // biases
    if (i >= 1216) return;
    float v;
    if (i < 64) v = ldf(embl_b, i, f);
    else if (i < 128) v = ldf(embr_b, i - 64, f);
    else if (i < 192) v = ldf(embrv_b, i - 128, f);
    else if (i < 320) v = ldf(outl_b, i - 192, f);
    else if (i < 448) v = ldf(head_b, i - 320, f);
    else if (i < 832) v = ldf(b1, i - 448, f);
    else v = ldf(b2, i - 832, f);
    g_bias[i] = v;
  } else {                        // fc weights
    if (i >= 32768) return;
    float v;
    if (i < 4096) v = ldf(f1a, i, f);
    else if (i < 16384) v = ldf(f2a, i - 4096, f);
    else if (i < 20480) v = ldf(f1b, i - 16384, f);
    else v = ldf(f2b_, i - 20480, f);
    g_fc[i] = v;
  }
}

// ---------------- NCHW -> NHWC transpose + bf16 canonicalization + pool partials
__global__ __launch_bounds__(256) void k_nchw2nhwc(const void* srcL, const void* srcR,
                                                   u16* __restrict__ dstL, u16* __restrict__ dstR) {
  __shared__ u16 tile[64][130];
  int f = g_flag;
  int w0 = blockIdx.x * 64;
  int h = blockIdx.y;
  int b = blockIdx.z & 1;
  int img = blockIdx.z >> 1;
  const void* src = img ? srcR : srcL;
  u16* dst = img ? dstR : dstL;
  int t = threadIdx.x;
  int wq = (t & 31) * 2, cb = t >> 5;
  for (int c0 = 0; c0 < 128; c0 += 8) {
    int c = c0 + cb;
    long base = (long)(b * 128 + c) * HW + h * Ww + w0 + wq;
    if (f) {
      float2 v = *reinterpret_cast<const float2*>((const float*)src + base);
      tile[wq][c] = f2b(v.x);
      tile[wq + 1][c] = f2b(v.y);
    } else {
      u32 v = *reinterpret_cast<const u32*>((const u16*)src + base);
      tile[wq][c] = (u16)v;
      tile[wq + 1][c] = (u16)(v >> 16);
    }
  }
  __syncthreads();
  int c = t & 127, wb = t >> 7;
  long obase = (long)b * HW + (long)h * Ww + w0;
  for (int w1i = 0; w1i < 64; w1i += 2) {
    int w = w1i + wb;
    dst[(obase + w) * 128 + c] = tile[w][c];
  }
  // SKN pool partials for left/right (sum over this block's 64 w at height h)
  if (t < 128) {
    float s = 0.f;
#pragma unroll
    for (int w = 0; w < 64; w++) s += b2f(tile[w][t]);
    g_ppart[((img * 2 + b) * 128 + t) * 1024 + (h * 8 + blockIdx.x)] = s;
  }
}

// ---------------- generic 1x1 conv as GEMM
template<int K, int N, bool RELU, bool NCHW_OUT>
__global__ __launch_bounds__(256) void k_gemm1x1(const u16* __restrict__ xt, const u16* __restrict__ w,
                                                 const float* __restrict__ bias, u16* __restrict__ out,
                                                 int wstride) {
  extern __shared__ __align__(16) char smem[];
  constexpr int SLOTS = (K * 2) / 16;
  constexpr int RB = K * 2;
  int t = threadIdx.x;
  long p0 = (long)blockIdx.x * 128;
  for (int u = t; u < 128 * SLOTS; u += 256) {
    int row = u / SLOTS, slot = u % SLOTS;
    int4 v = *reinterpret_cast<const int4*>(xt + (p0 + row) * K + slot * 8);
    *reinterpret_cast<int4*>(smem + (((u32)(row * RB + slot * 16)) ^ ((row & 7) << 4))) = v;
  }
  __syncthreads();
  int wid = t >> 6, lane = t & 63, l15 = lane & 15, l4 = lane >> 4;
  constexpr int WAVES_M = (N == 64) ? 4 : 2;
  constexpr int MF = (128 / WAVES_M) / 16;
  int wm = (N == 64) ? wid : (wid >> 1);
  int wn = (N == 64) ? 0 : (wid & 1);
  int prow0 = wm * (128 / WAVES_M);
  int ocol0 = wn * 64;
  f32x4 zz = {0.f, 0.f, 0.f, 0.f};
  f32x4 acc[MF][4];
#pragma unroll
  for (int m = 0; m < MF; m++)
#pragma unroll
    for (int n = 0; n < 4; n++) acc[m][n] = zz;
#pragma unroll
  for (int k0 = 0; k0 < K; k0 += 32) {
    bf16x8 a[MF], bw[4];
#pragma unroll
    for (int m = 0; m < MF; m++) {
      int row = prow0 + m * 16 + l15;
      a[m] = ld8(smem + (((u32)(row * RB + (k0 + l4 * 8) * 2)) ^ ((row & 7) << 4)));
    }
#pragma unroll
    for (int n = 0; n < 4; n++) {
      int o = ocol0 + n * 16 + l15;
      bw[n] = ld8(w + (long)o * wstride + k0 + l4 * 8);
    }
#pragma unroll
    for (int m = 0; m < MF; m++)
#pragma unroll
      for (int n = 0; n < 4; n++) acc[m][n] = MFMA16(a[m], bw[n], acc[m][n]);
  }
  if constexpr (!NCHW_OUT) {
#pragma unroll
    for (int m = 0; m < MF; m++)
#pragma unroll
      for (int n = 0; n < 4; n++) {
        int o = ocol0 + n * 16 + l15;
        float bb = bias[o];
#pragma unroll
        for (int r = 0; r < 4; r++) {
          long p = p0 + prow0 + m * 16 + l4 * 4 + r;
          float v = acc[m][n][r] + bb;
          if (RELU) v = fmaxf(v, 0.f);
          out[p * N + o] = f2b(v);
        }
      }
  } else {
    __syncthreads();
    u16* tb = reinterpret_cast<u16*>(smem) + wid * (64 * 66);
#pragma unroll
    for (int m = 0; m < MF; m++)
#pragma unroll
      for (int n = 0; n < 4; n++) {
        float bb = bias[ocol0 + n * 16 + l15];
#pragma unroll
        for (int r = 0; r < 4; r++) {
          int pl = m * 16 + l4 * 4 + r;
          float v = acc[m][n][r] + bb;
          if (RELU) v = fmaxf(v, 0.f);
          tb[(n * 16 + l15) * 66 + pl] = f2b(v);
        }
      }
    __syncthreads();
    int bq = (int)(p0 / HW);
    int rem = (int)(p0 % HW);
    int hq = rem / Ww, wq0 = rem % Ww;
    for (int o = 0; o < 64; o++) {
      out[((long)(bq * 128 + ocol0 + o)) * HW + hq * Ww + wq0 + prow0 + lane] = tb[o * 66 + lane];
    }
  }
}

// ---------------- fused Q/K/V embedding GEMMs (one launch, blockIdx.y selects branch)
__global__ __launch_bounds__(256) void k_emb3(const u16* __restrict__ leftT, const u16* __restrict__ rightT,
                                              const u16* __restrict__ gw, const float* __restrict__ gbias,
                                              u16* __restrict__ QT, u16* __restrict__ KT, u16* __restrict__ VrT) {
  extern __shared__ __align__(16) char smem[];
  int br = blockIdx.y;
  const u16* xt = (br == 0) ? leftT : rightT;
  const u16* w = gw + ((br == 0) ? EMB_L : (br == 1) ? EMB_R : EMB_RV);
  const float* bias = gbias + ((br == 0) ? B_EMBL : (br == 1) ? B_EMBR : B_EMBRV);
  u16* out = (br == 0) ? QT : (br == 1) ? KT : VrT;
  int t = threadIdx.x;
  long p0 = (long)blockIdx.x * 128;
  for (int u = t; u < 2048; u += 256) {
    int row = u >> 4, slot = u & 15;
    int4 v = *reinterpret_cast<const int4*>(xt + (p0 + row) * 128 + slot * 8);
    *reinterpret_cast<int4*>(smem + (((u32)(row * 256 + slot * 16)) ^ ((row & 7) << 4))) = v;
  }
  __syncthreads();
  int wid = t >> 6, lane = t & 63, l15 = lane & 15, l4 = lane >> 4;
  int prow0 = wid * 32;
  f32x4 zz = {0.f, 0.f, 0.f, 0.f};
  f32x4 acc[2][4];
#pragma unroll
  for (int m = 0; m < 2; m++)
#pragma unroll
    for (int n = 0; n < 4; n++) acc[m][n] = zz;
#pragma unroll
  for (int k0 = 0; k0 < 128; k0 += 32) {
    bf16x8 a[2], bw[4];
#pragma unroll
    for (int m = 0; m < 2; m++) {
      int row = prow0 + m * 16 + l15;
      a[m] = ld8(smem + (((u32)(row * 256 + (k0 + l4 * 8) * 2)) ^ ((row & 7) << 4)));
    }
#pragma unroll
    for (int n = 0; n < 4; n++) {
      int o = n * 16 + l15;
      bw[n] = ld8(w + (long)o * 128 + k0 + l4 * 8);
    }
#pragma unroll
    for (int m = 0; m < 2; m++)
#pragma unroll
      for (int n = 0; n < 4; n++) acc[m][n] = MFMA16(a[m], bw[n], acc[m][n]);
  }
#pragma unroll
  for (int m = 0; m < 2; m++)
#pragma unroll
    for (int n = 0; n < 4; n++) {
      int o = n * 16 + l15;
      float bb = bias[o];
#pragma unroll
      for (int r = 0; r < 4; r++) {
        long p = p0 + prow0 + m * 16 + l4 * 4 + r;
        out[p * 64 + o] = f2b(acc[m][n][r] + bb);
      }
    }
}

// ---------------- head: relu(leftT @ Wh[:,:128]^T + rightT @ Wh[:,128:]^T + b), NHWC out
// out may alias rt (in-place safe: each block reads/writes only its own rows).
__global__ __launch_bounds__(256) void k_head(const u16* lt, const u16* rt,
                                              const u16* __restrict__ wh, const float* __restrict__ bh,
                                              u16* out) {
  extern __shared__ __align__(16) char smem[];
  int t = threadIdx.x;
  long p0 = (long)blockIdx.x * 128;
  for (int u = t; u < 2048; u += 256) {
    int row = u >> 4, slot = u & 15;
    u32 db = ((u32)(row * 256 + slot * 16)) ^ ((row & 7) << 4);
    *reinterpret_cast<int4*>(smem + db) = *reinterpret_cast<const int4*>(lt + (p0 + row) * 128 + slot * 8);
    *reinterpret_cast<int4*>(smem + 32768 + db) = *reinterpret_cast<const int4*>(rt + (p0 + row) * 128 + slot * 8);
  }
  __syncthreads();
  int wid = t >> 6, lane = t & 63, l15 = lane & 15, l4 = lane >> 4;
  int prow0 = (wid >> 1) * 64, ocol0 = (wid & 1) * 64;
  f32x4 zz = {0.f, 0.f, 0.f, 0.f};
  f32x4 acc[4][4];
#pragma unroll
  for (int m = 0; m < 4; m++)
#pragma unroll
    for (int n = 0; n < 4; n++) acc[m][n] = zz;
#pragma unroll
  for (int kk = 0; kk < 8; kk++) {
    int k0 = kk * 32;
    const char* sb = smem + ((kk >= 4) ? 32768 : 0);
    int kl = k0 & 127;
    bf16x8 a[4], bw[4];
#pragma unroll
    for (int m = 0; m < 4; m++) {
      int row = prow0 + m * 16 + l15;
      a[m] = ld8(sb + (((u32)(row * 256 + (kl + l4 * 8) * 2)) ^ ((row & 7) << 4)));
    }
#pragma unroll
    for (int n = 0; n < 4; n++) {
      int o = ocol0 + n * 16 + l15;
      bw[n] = ld8(wh + o * 256 + k0 + l4 * 8);
    }
#pragma unroll
    for (int m = 0; m < 4; m++)
#pragma unroll
      for (int n = 0; n < 4; n++) acc[m][n] = MFMA16(a[m], bw[n], acc[m][n]);
  }
  __syncthreads();
#pragma unroll
  for (int m = 0; m < 4; m++)
#pragma unroll
    for (int n = 0; n < 4; n++) {
      int o = ocol0 + n * 16 + l15;
      float bb = bh[o];
#pragma unroll
      for (int r = 0; r < 4; r++) {
        long p = p0 + prow0 + m * 16 + l4 * 4 + r;
        float v = fmaxf(acc[m][n][r] + bb, 0.f);
        out[p * 128 + o] = f2b(v);
      }
    }
}

// ---------------- windowed cross-attention
__global__ __launch_bounds__(256) void k_attn(const u16* __restrict__ qt, const u16* __restrict__ kt,
                                              const u16* __restrict__ vt, u16* __restrict__ outT) {
  extern __shared__ __align__(16) char smem[];
  int n = blockIdx.x, h = blockIdx.y, b = blockIdx.z;
  long rb = ((long)(b * Hh + h)) * Ww + n * 128;
  int t = threadIdx.x;
  for (int u = t; u < 1024; u += 256) {
    int row = u >> 3, slot = u & 7;
    u32 db = ((u32)(row * 128 + slot * 16)) ^ ((row & 7) << 4);
    *reinterpret_cast<int4*>(smem + db) = *reinterpret_cast<const int4*>(qt + (rb + row) * 64 + slot * 8);
    *reinterpret_cast<int4*>(smem + 16384 + db) = *reinterpret_cast<const int4*>(kt + (rb + row) * 64 + slot * 8);
  }
  __syncthreads();
  int wid = t >> 6, lane = t & 63, l15 = lane & 15, l4 = lane >> 4;
  int q0 = wid * 32;
  f32x4 zz = {0.f, 0.f, 0.f, 0.f};
  f32x4 sc[2][8];
#pragma unroll
  for (int m = 0; m < 2; m++)
#pragma unroll
    for (int nf = 0; nf < 8; nf++) sc[m][nf] = zz;
#pragma unroll
  for (int k0 = 0; k0 < 64; k0 += 32) {
    bf16x8 aq[2], bk[8];
#pragma unroll
    for (int m = 0; m < 2; m++) {
      int row = q0 + m * 16 + l15;
      aq[m] = ld8(smem + (((u32)(row * 128 + (k0 + l4 * 8) * 2)) ^ ((row & 7) << 4)));
    }
#pragma unroll
    for (int nf = 0; nf < 8; nf++) {
      int row = nf * 16 + l15;
      bk[nf] = ld8(smem + 16384 + (((u32)(row * 128 + (k0 + l4 * 8) * 2)) ^ ((row & 7) << 4)));
    }
#pragma unroll
    for (int m = 0; m < 2; m++)
#pragma unroll
      for (int nf = 0; nf < 8; nf++) sc[m][nf] = MFMA16(aq[m], bk[nf], sc[m][nf]);
  }
  float rsum[2][4];
#pragma unroll
  for (int m = 0; m < 2; m++) {
#pragma unroll
    for (int r = 0; r < 4; r++) {
      float mx = -3.0e38f;
#pragma unroll
      for (int nf = 0; nf < 8; nf++) mx = fmaxf(mx, sc[m][nf][r]);
      mx = fmaxf(mx, __shfl_xor(mx, 1));
      mx = fmaxf(mx, __shfl_xor(mx, 2));
      mx = fmaxf(mx, __shfl_xor(mx, 4));
      mx = fmaxf(mx, __shfl_xor(mx, 8));
      int ql = q0 + m * 16 + l4 * 4 + r;
      float ssum = 0.f;
#pragma unroll
      for (int nf = 0; nf < 8; nf++) {
        float e = __expf(sc[m][nf][r] - mx);
        ssum += e;
        int k = nf * 16 + l15;
        *reinterpret_cast<u16*>(smem + 32768 + (((u32)(ql * 256 + k * 2)) ^ ((ql & 7) << 4))) = f2b(e);
      }
      ssum += __shfl_xor(ssum, 1);
      ssum += __shfl_xor(ssum, 2);
      ssum += __shfl_xor(ssum, 4);
      ssum += __shfl_xor(ssum, 8);
      rsum[m][r] = ssum;
    }
  }
  __syncthreads();
  for (int u = t; u < 8192; u += 256) {
    int k = u >> 6, c = u & 63;
    u16 v = vt[(rb + k) * 64 + c];
    *reinterpret_cast<u16*>(smem + (((u32)(c * 256 + k * 2)) ^ ((c & 7) << 4))) = v;
  }
  __syncthreads();
  f32x4 ov[2][4];
#pragma unroll
  for (int m = 0; m < 2; m++)
#pragma unroll
    for (int nf = 0; nf < 4; nf++) ov[m][nf] = zz;
#pragma unroll
  for (int k0 = 0; k0 < 128; k0 += 32) {
    bf16x8 ap[2], bv[4];
#pragma unroll
    for (int m = 0; m < 2; m++) {
      int row = q0 + m * 16 + l15;
      ap[m] = ld8(smem + 32768 + (((u32)(row * 256 + (k0 + l4 * 8) * 2)) ^ ((row & 7) << 4)));
    }
#pragma unroll
    for (int nf = 0; nf < 4; nf++) {
      int c = nf * 16 + l15;
      bv[nf] = ld8(smem + (((u32)(c * 256 + (k0 + l4 * 8) * 2)) ^ ((c & 7) << 4)));
    }
#pragma unroll
    for (int m = 0; m < 2; m++)
#pragma unroll
      for (int nf = 0; nf < 4; nf++) ov[m][nf] = MFMA16(ap[m], bv[nf], ov[m][nf]);
  }
#pragma unroll
  for (int m = 0; m < 2; m++)
#pragma unroll
    for (int nf = 0; nf < 4; nf++)
#pragma unroll
      for (int r = 0; r < 4; r++) {
        int q = q0 + m * 16 + l4 * 4 + r;
        int c = nf * 16 + l15;
        outT[(rb + q) * 64 + c] = f2b(ov[m][nf][r] / rsum[m][r]);
      }
}

// ---------------- conv1x9: BARRIER-FREE main loop. x-tile LDS-resident (read-only after one
// prologue barrier); each wave stages its OWN 64-o weight slice (K=32/step) into a private
// 2-slot LDS region via global_load_lds, self-timed with per-wave counted vmcnt. T5 setprio.
template<bool RELU, bool HASRES, bool NCHW_OUT>
__global__ __launch_bounds__(256) void k_conv1x9(const u16* __restrict__ xin, const u16* __restrict__ wp9,
                                                 const float* __restrict__ bias, const u16* __restrict__ res,
                                                 u16* __restrict__ out) {
  __shared__ __align__(16) char xs[34816];   // 136 rows x 256B, XOR-swizzled
  __shared__ __align__(16) char wbuf[32768]; // 4 waves x 2 slots x 4KB private weight tiles
  int w0 = blockIdx.x * 128;
  int h = blockIdx.y, b = blockIdx.z;
  long rowg = ((long)(b * Hh + h)) * Ww;
  int t = threadIdx.x;
  int wid = t >> 6, lane = t & 63;
  int o0w = (wid & 1) * 64;
  char* wbase = wbuf + wid * 8192;
  // stage step s: o0w..o0w+63 x K=32 (tap=s>>2, kk=s&3) into private slot (s&1).
  // physical 16B slot p holds logical k-slot (p - (o'>>1))&3  (rotation -> uniform banks).
  auto stage = [&](int s) {
    int tap = s >> 2, kk = s & 3;
    const u16* base = wp9 + tap * 16384 + (long)o0w * 128 + kk * 32;
#pragma unroll
    for (int j = 0; j < 4; j++) {
      int u = j * 64 + lane;           // 16B unit 0..255
      int op = u >> 2, p = u & 3;
      int l = (p - (op >> 1)) & 3;
      gload16(base + op * 128 + l * 8, wbase + (s & 1) * 4096 + j * 1024);
    }
  };
  // x-tile staging (once)
  for (int u = t; u < 2176; u += 256) {
    int row = u >> 4, slot = u & 15;
    int wg = w0 - 4 + row;
    int4 v{0, 0, 0, 0};
    if (wg >= 0 && wg < Ww) v = *reinterpret_cast<const int4*>(xin + (rowg + wg) * 128 + slot * 8);
    *reinterpret_cast<int4*>(xs + (((u32)(row * 256 + slot * 16)) ^ ((row & 7) << 4))) = v;
  }
  stage(0);
  __syncthreads();   // xs visible to all; drains vmcnt (stage(0) landed)
  int l15 = lane & 15, l4 = lane >> 4;
  int p0w = (wid >> 1) * 64;
  f32x4 zz = {0.f, 0.f, 0.f, 0.f};
  f32x4 acc[4][4];
#pragma unroll
  for (int m = 0; m < 4; m++)
#pragma unroll
    for (int n = 0; n < 4; n++) acc[m][n] = zz;
#pragma unroll 1
  for (int s = 0; s < 36; s++) {
    if (s < 35) {
      stage(s + 1);
      asm volatile("s_waitcnt vmcnt(4)" ::: "memory");  // own stage(s) landed; stage(s+1) in flight
    } else {
      asm volatile("s_waitcnt vmcnt(0)" ::: "memory");
    }
    int tap = s >> 2, kk = s & 3;
    const char* wb = wbase + (s & 1) * 4096;
    bf16x8 a[4], bw[4];
#pragma unroll
    for (int n = 0; n < 4; n++) {
      int op = n * 16 + l15;
      int p = (l4 + (op >> 1)) & 3;
      bw[n] = ld8(wb + op * 64 + p * 16);
    }
#pragma unroll
    for (int m = 0; m < 4; m++) {
      int row = p0w + m * 16 + l15 + tap;
      a[m] = ld8(xs + (((u32)(row * 256 + kk * 64 + l4 * 16)) ^ ((row & 7) << 4)));
    }
    __builtin_amdgcn_s_setprio(1);
#pragma unroll
    for (int m = 0; m < 4; m++)
#pragma unroll
      for (int n = 0; n < 4; n++) acc[m][n] = MFMA16(a[m], bw[n], acc[m][n]);
    __builtin_amdgcn_s_setprio(0);
  }
  float bb[4];
#pragma unroll
  for (int n = 0; n < 4; n++) bb[n] = bias[o0w + n * 16 + l15];
  if constexpr (!NCHW_OUT) {
#pragma unroll
    for (int m = 0; m < 4; m++)
#pragma unroll
      for (int n = 0; n < 4; n++) {
        int o = o0w + n * 16 + l15;
#pragma unroll
        for (int r = 0; r < 4; r++) {
          int p = w0 + p0w + m * 16 + l4 * 4 + r;
          float v = acc[m][n][r] + bb[n];
          if (RELU) v = fmaxf(v, 0.f);
          if (HASRES) v += b2f(res[(rowg + p) * 128 + o]);
          out[(rowg + p) * 128 + o] = f2b(v);
        }
      }
  } else {
    __syncthreads();   // wave drift: all xs reads done before reuse as transpose staging
    u16* tb = reinterpret_cast<u16*>(xs) + wid * (64 * 66);
#pragma unroll
    for (int m = 0; m < 4; m++)
#pragma unroll
      for (int n = 0; n < 4; n++) {
        int o = o0w + n * 16 + l15;
#pragma unroll
        for (int r = 0; r < 4; r++) {
          int pl = m * 16 + l4 * 4 + r;
          int p = w0 + p0w + pl;
          float v = acc[m][n][r] + bb[n];
          if (RELU) v = fmaxf(v, 0.f);
          if (HASRES) v += b2f(res[(rowg + p) * 128 + o]);
          tb[(n * 16 + l15) * 66 + pl] = f2b(v);
        }
      }
    __syncthreads();
    for (int o = 0; o < 64; o++) {
      out[((long)(b * 128 + o0w + o)) * HW + h * Ww + w0 + p0w + lane] = tb[o * 66 + lane];
    }
  }
}

// ---------------- pools: ts 0/1 reduce transpose partials; ts 2/3 scan lfw/mixed (bf16 NCHW)
__global__ __launch_bounds__(256) void k_pool(const u16* __restrict__ lfw, const u16* __restrict__ mixed) {
  int c = blockIdx.x, b = blockIdx.y, ts = blockIdx.z;
  float s = 0.f;
  if (ts < 2) {
    const float* pp = g_ppart + ((ts * 2 + b) * 128 + c) * 1024;
    for (int i = threadIdx.x; i < 1024; i += 256) s += pp[i];
  } else {
    long base = ((long)(b * 128 + c)) * HW;
    const u16* pu = (ts == 2) ? lfw + base : mixed + base;
    for (int i = threadIdx.x * 8; i < HW; i += 2048) {
      union { int4 v; u16 u[8]; } x;
      x.v = *reinterpret_cast<const int4*>(pu + i);
#pragma unroll
      for (int j = 0; j < 8; j++) s += b2f(x.u[j]);
    }
  }
#pragma unroll
  for (int m = 1; m < 64; m <<= 1) s += __shfl_xor(s, m);
  __shared__ float red[4];
  if ((threadIdx.x & 63) == 0) red[threadIdx.x >> 6] = s;
  __syncthreads();
  if (threadIdx.x == 0)
    g_pools[(ts * 2 + b) * 128 + c] = (red[0] + red[1] + red[2] + red[3]) * (1.f / HW);
}

// ---------------- SKN gate MLP + branch softmax (tiny)
__global__ void k_gate() {
  __shared__ float sv[128], zv[32];
  int b = blockIdx.x, s = blockIdx.y;
  int t = threadIdx.x;
  sv[t] = g_pools[(s * 2 + b) * 128 + t] + g_pools[(4 + b) * 128 + t] + g_pools[(6 + b) * 128 + t];
  __syncthreads();
  const float* fc1 = g_fc + (s ? FC1B : FC1A);
  const float* fc2 = g_fc + (s ? FC2B : FC2A);
  if (t < 32) {
    float z = 0.f;
    for (int c = 0; c < 128; c++) z += fc1[t * 128 + c] * sv[c];
    zv[t] = (z > 0.f) ? z : 0.01f * z;
  }
  __syncthreads();
  float ab[3];
#pragma unroll
  for (int i = 0; i < 3; i++) {
    float a = 0.f;
    for (int j = 0; j < 32; j++) a += fc2[(i * 128 + t) * 32 + j] * zv[j];
    ab[i] = a;
  }
  float mx = fmaxf(ab[0], fmaxf(ab[1], ab[2]));
  float e0 = __expf(ab[0] - mx), e1 = __expf(ab[1] - mx), e2 = __expf(ab[2] - mx);
  float inv = 1.f / (e0 + e1 + e2);
  g_gates[((s * 2 + b) * 3 + 0) * 128 + t] = e0 * inv;
  g_gates[((s * 2 + b) * 3 + 1) * 128 + t] = e1 * inv;
  g_gates[((s * 2 + b) * 3 + 2) * 128 + t] = e2 * inv;
}

// ---------------- final weighted sums -> d_out (flag dtype)
__global__ __launch_bounds__(256) void k_skn_out(const void* left, const void* right,
                                                 const u16* __restrict__ lfw, const u16* __restrict__ mixed,
                                                 void* doutv) {
  int chunk = blockIdx.x, c = blockIdx.y, b = blockIdx.z;
  int f = g_flag;
  const float* g1 = g_gates + (b * 3) * 128 + c;
  const float* g2 = g_gates + ((2 + b) * 3) * 128 + c;
  float a10 = g1[0], a11 = g1[128], a12 = g1[256];
  float a20 = g2[0], a21 = g2[128], a22 = g2[256];
  long off = ((long)(b * 128 + c)) * HW + chunk * 2048 + threadIdx.x * 8;
  float xl[8], xr[8];
  if (f) {
    const float* L = (const float*)left + off;
    const float* R = (const float*)right + off;
    float4 a0 = *reinterpret_cast<const float4*>(L);
    float4 a1 = *reinterpret_cast<const float4*>(L + 4);
    float4 r0 = *reinterpret_cast<const float4*>(R);
    float4 r1 = *reinterpret_cast<const float4*>(R + 4);
    xl[0]=a0.x; xl[1]=a0.y; xl[2]=a0.z; xl[3]=a0.w; xl[4]=a1.x; xl[5]=a1.y; xl[6]=a1.z; xl[7]=a1.w;
    xr[0]=r0.x; xr[1]=r0.y; xr[2]=r0.z; xr[3]=r0.w; xr[4]=r1.x; xr[5]=r1.y; xr[6]=r1.z; xr[7]=r1.w;
  } else {
    union { int4 v; u16 u[8]; } a, r;
    a.v = *reinterpret_cast<const int4*>((const u16*)left + off);
    r.v = *reinterpret_cast<const int4*>((const u16*)right + off);
#pragma unroll
    for (int j = 0; j < 8; j++) { xl[j] = b2f(a.u[j]); xr[j] = b2f(r.u[j]); }
  }
  union { int4 v; u16 u[8]; } vw, vm;
  vw.v = *reinterpret_cast<const int4*>(lfw + off);
  vm.v = *reinterpret_cast<const int4*>(mixed + off);
  float ol[8], orr[8];
#pragma unroll
  for (int j = 0; j < 8; j++) {
    float fw = b2f(vw.u[j]), fm = b2f(vm.u[j]);
    ol[j] = a10 * xl[j] + a11 * fw + a12 * fm;
    orr[j] = a20 * xr[j] + a21 * fw + a22 * fm;
  }
  if (f) {
    float* fo = (float*)doutv;
    *reinterpret_cast<float4*>(fo + off) = make_float4(ol[0], ol[1], ol[2], ol[3]);
    *reinterpret_cast<float4*>(fo + off + 4) = make_float4(ol[4], ol[5], ol[6], ol[7]);
    *reinterpret_cast<float4*>(fo + FULL + off) = make_float4(orr[0], orr[1], orr[2], orr[3]);
    *reinterpret_cast<float4*>(fo + FULL + off + 4) = make_float4(orr[4], orr[5], orr[6], orr[7]);
  } else {
    u16* bo = (u16*)doutv;
    union { int4 v; u16 u[8]; } o1, o2;
#pragma unroll
    for (int j = 0; j < 8; j++) { o1.u[j] = f2b(ol[j]); o2.u[j] = f2b(orr[j]); }
    *reinterpret_cast<int4*>(bo + off) = o1.v;
    *reinterpret_cast<int4*>(bo + FULL + off) = o2.v;
  }
}

extern "C" void kernel_launch(void* const* d_in, const int* in_sizes, int n_in,
                              void* d_out, int out_size, void* d_ws, size_t ws_size,
                              hipStream_t stream) {
  (void)in_sizes; (void)n_in; (void)out_size; (void)d_ws; (void)ws_size;
  const void* left    = d_in[0];
  const void* right   = d_in[1];

  u16* gbuf = nullptr;
  (void)hipGetSymbolAddress((void**)&gbuf, HIP_SYMBOL(g_buf));
  u16* gw = nullptr;
  (void)hipGetSymbolAddress((void**)&gw, HIP_SYMBOL(g_w));
  float* gbias = nullptr;
  (void)hipGetSymbolAddress((void**)&gbias, HIP_SYMBOL(g_bias));

  // scratch plan (no D2D copies; end-state lfw/mixed in g_buf, d_out free before k_skn_out):
  u16* du = (u16*)d_out;
  u16* leftT   = du;                    // [0, FULL)        dead after k_head
  u16* rA      = du;                    // [0, FULL)        conv ping (after leftT dead)
  u16* rightT  = du + FULL;             // [FULL, 2FULL)    dead after k_head (head emits in-place)
  u16* xG      = du + FULL;             // [FULL, 2FULL)    head output / conv pong
  u16* QT      = gbuf;                  // [0, HALF)        dead after attn
  u16* KT      = gbuf + HALF;           // [HALF, FULL)     dead after attn
  u16* VrT     = gbuf + FULL;           // [FULL, 1.5FULL)  dead after attn
  u16* warpedT = gbuf + FULL + HALF;    // [1.5FULL, 2FULL) dead after out_l
  u16* lfw     = gbuf;                  // [0, FULL)        NCHW, lives to end (QT/KT dead)
  u16* mixed   = gbuf + FULL;           // [FULL, 2FULL)    NCHW, lives to end (VrT/warped dead)

  k_detect<<<dim3(1), dim3(64), 0, stream>>>(left);
  k_pack<<<dim3(3456, 4), dim3(256), 0, stream>>>(
      d_in[14], d_in[16], d_in[2], d_in[4], d_in[8], d_in[10], d_in[12],
      d_in[3], d_in[5], d_in[9], d_in[11], d_in[13], d_in[15], d_in[17],
      d_in[18], d_in[19], d_in[20], d_in[21]);
  k_nchw2nhwc<<<dim3(8, 128, 4), dim3(256), 0, stream>>>(left, right, leftT, rightT);
  k_emb3<<<dim3(1024, 3), dim3(256), 32768, stream>>>(leftT, rightT, gw, gbias, QT, KT, VrT);
  k_head<<<dim3(1024), dim3(256), 65536, stream>>>(leftT, rightT, gw + HEAD, gbias + B_HEAD, xG);  // in-place over rightT
  k_attn<<<dim3(4, 128, 2), dim3(256), 65536, stream>>>(QT, KT, VrT, warpedT);          // QT,KT,VrT dead
  k_gemm1x1<64, 128, true, true><<<dim3(1024), dim3(256), 33792, stream>>>(warpedT, gw + OUTL, gbias + B_OUTL, lfw, 64);
  for (int i = 0; i < 3; i++) {
    k_conv1x9<true, false, false><<<dim3(4, 128, 2), dim3(256), 0, stream>>>(
        xG, gw + BODY + (long)(i * 2 + 0) * 9 * 16384, gbias + B_B1 + i * 128, nullptr, rA);
    if (i < 2)
      k_conv1x9<false, true, false><<<dim3(4, 128, 2), dim3(256), 0, stream>>>(
          rA, gw + BODY + (long)(i * 2 + 1) * 9 * 16384, gbias + B_B2 + i * 128, xG, xG);
    else
      k_conv1x9<false, true, true><<<dim3(4, 128, 2), dim3(256), 0, stream>>>(
          rA, gw + BODY + (long)(i * 2 + 1) * 9 * 16384, gbias + B_B2 + i * 128, xG, mixed);
  }
  k_pool<<<dim3(128, 2, 4), dim3(256), 0, stream>>>(lfw, mixed);
  k_gate<<<dim3(2, 2), dim3(128), 0, stream>>>();
  k_skn_out<<<dim3(32, 128, 2), dim3(256), 0, stream>>>(left, right, lfw, mixed, d_out);
}

// Round 9
// 542.940 us; speedup vs baseline: 1.1751x; 1.0881x over previous
//
#include <hip/hip_runtime.h>
#include <hip/hip_bf16.h>

typedef __attribute__((ext_vector_type(8))) short bf16x8;
typedef __attribute__((ext_vector_type(4))) float f32x4;
typedef unsigned short u16;
typedef unsigned int u32;

#define DI __device__ __forceinline__
#define MFMA16(a, b, c) __builtin_amdgcn_mfma_f32_16x16x32_bf16((a), (b), (c), 0, 0, 0)

constexpr int Hh = 128, Ww = 512;
constexpr int HW = 65536;                // H*W
constexpr long FULL = 16777216;          // B*C*H*W = 2*128*128*512
constexpr long HALF = 8388608;

// canonical staging (independent of harness dtype)
__device__ __align__(16) u16 g_buf[2 * FULL];   // 64 MB scratch
__device__ __align__(16) u16 g_w[950272];       // all weights, bf16
__device__ __align__(16) float g_bias[1216];    // all biases, f32
__device__ __align__(16) float g_fc[32768];     // SKN fc weights, f32
__device__ __align__(16) float g_pools[1024];
__device__ __align__(16) float g_gates[1536];
__device__ __align__(16) float g_ppart[524288]; // [ts2][b2][c128][blk1024] partial pools
__device__ int g_flag;                          // 1 = inputs are f32, 0 = bf16

// g_w offsets (u16 elements)
constexpr int EMB_L = 0, EMB_R = 8192, EMB_RV = 16384, HEAD = 24576, OUTL = 57344, BODY = 65536;
// g_bias offsets
constexpr int B_EMBL = 0, B_EMBR = 64, B_EMBRV = 128, B_OUTL = 192, B_HEAD = 320, B_B1 = 448, B_B2 = 832;
// g_fc offsets
constexpr int FC1A = 0, FC2A = 4096, FC1B = 16384, FC2B = 20480;

DI float b2f(u16 u) { union { u32 i; float f; } v; v.i = (u32)u << 16; return v.f; }
DI u16 f2b(float f) {
  union { float fl; u32 u; } v; v.fl = f;
  return (u16)((v.u + 0x7FFFu + ((v.u >> 16) & 1u)) >> 16);
}
DI float ldf(const void* p, long i, int f) {
  return f ? ((const float*)p)[i] : b2f(((const u16*)p)[i]);
}
DI bf16x8 ld8(const void* p) { return *reinterpret_cast<const bf16x8*>(p); }
DI void gload16(const u16* src, char* lds_dst) {
  __builtin_amdgcn_global_load_lds(
      (const __attribute__((address_space(1))) void*)src,
      (__attribute__((address_space(3))) void*)lds_dst, 16, 0, 0);
}

// ---------------- dtype detection
__global__ void k_detect(const void* left) {
  if (threadIdx.x != 0 || blockIdx.x != 0) return;
  const u16* pu = (const u16*)left;
  int okb = 0;
  for (int i = 0; i < 256; i++) {
    float x = b2f(pu[i]);
    float a = fabsf(x);
    if (x == 0.f || (a > 1e-8f && a < 1e4f)) okb++;
  }
  g_flag = (okb >= 230) ? 0 : 1;
}

// ---------------- pack ALL weights/biases to canonical buffers (flag-aware)
__global__ void k_pack(const void* w1, const void* w2, const void* embl, const void* embr,
                       const void* embrv, const void* outl, const void* head,
                       const void* embl_b, const void* embr_b, const void* embrv_b,
                       const void* outl_b, const void* head_b, const void* b1, const void* b2,
                       const void* f1a, const void* f2a, const void* f1b, const void* f2b_) {
  int f = g_flag;
  int i = blockIdx.x * 256 + threadIdx.x;
  int job = blockIdx.y;
  if (job == 0) {                 // body weights repack: wp[(blk*2+conv)*9+t][o][c]
    if (i >= 884736) return;
    int c = i & 127, o = (i >> 7) & 127;
    int rest = i >> 14;
    int t = rest % 9, bc = rest / 9;
    const void* src = (bc & 1) ? w2 : w1;
    int blk = bc >> 1;
    g_w[BODY + i] = f2b(ldf(src, (((long)(blk * 128 + o) * 128 + c)) * 9 + t, f));
  } else if (job == 1) {          // 1x1 weights (already [O][C] row-major)
    if (i >= 65536) return;
    float v;
    if (i < 8192) v = ldf(embl, i, f);
    else if (i < 16384) v = ldf(embr, i - 8192, f);
    else if (i < 24576) v = ldf(embrv, i - 16384, f);
    else if (i < 57344) v = ldf(head, i - 24576, f);
    else v = ldf(outl, i - 57344, f);
    g_w[i] = f2b(v);
  } else if (job == 2) {          // biases
    if (i >= 1216) return;
    float v;
    if (i < 64) v = ldf(embl_b, i, f);
    else if (i < 128) v = ldf(embr_b, i - 64, f);
    else if (i < 192) v = ldf(embrv_b, i - 128, f);
    else if (i < 320) v = ldf(outl_b, i - 192, f);
    else if (i < 448) v = ldf(head_b, i - 320, f);
    else if (i < 832) v = ldf(b1, i - 448, f);
    else v = ldf(b2, i - 832, f);
    g_bias[i] = v;
  } else {                        // fc weights
    if (i >= 32768) return;
    float v;
    if (i < 4096) v = ldf(f1a, i, f);
    else if (i < 16384) v = ldf(f2a, i - 4096, f);
    else if (i < 20480) v = ldf(f1b, i - 16384, f);
    else v = ldf(f2b_, i - 20480, f);
    g_fc[i] = v;
  }
}

// ---------------- NCHW -> NHWC transpose + bf16 canonicalization + pool partials
__global__ __launch_bounds__(256) void k_nchw2nhwc(const void* srcL, const void* srcR,
                                                   u16* __restrict__ dstL, u16* __restrict__ dstR) {
  __shared__ u16 tile[64][130];
  int f = g_flag;
  int w0 = blockIdx.x * 64;
  int h = blockIdx.y;
  int b = blockIdx.z & 1;
  int img = blockIdx.z >> 1;
  const void* src = img ? srcR : srcL;
  u16* dst = img ? dstR : dstL;
  int t = threadIdx.x;
  int wq = (t & 31) * 2, cb = t >> 5;
  for (int c0 = 0; c0 < 128; c0 += 8) {
    int c = c0 + cb;
    long base = (long)(b * 128 + c) * HW + h * Ww + w0 + wq;
    if (f) {
      float2 v = *reinterpret_cast<const float2*>((const float*)src + base);
      tile[wq][c] = f2b(v.x);
      tile[wq + 1][c] = f2b(v.y);
    } else {
      u32 v = *reinterpret_cast<const u32*>((const u16*)src + base);
      tile[wq][c] = (u16)v;
      tile[wq + 1][c] = (u16)(v >> 16);
    }
  }
  __syncthreads();
  int c = t & 127, wb = t >> 7;
  long obase = (long)b * HW + (long)h * Ww + w0;
  for (int w1i = 0; w1i < 64; w1i += 2) {
    int w = w1i + wb;
    dst[(obase + w) * 128 + c] = tile[w][c];
  }
  // SKN pool partials for left/right (sum over this block's 64 w at height h)
  if (t < 128) {
    float s = 0.f;
#pragma unroll
    for (int w = 0; w < 64; w++) s += b2f(tile[w][t]);
    g_ppart[((img * 2 + b) * 128 + t) * 1024 + (h * 8 + blockIdx.x)] = s;
  }
}

// ---------------- generic 1x1 conv as GEMM
template<int K, int N, bool RELU, bool NCHW_OUT>
__global__ __launch_bounds__(256) void k_gemm1x1(const u16* __restrict__ xt, const u16* __restrict__ w,
                                                 const float* __restrict__ bias, u16* __restrict__ out,
                                                 int wstride) {
  extern __shared__ __align__(16) char smem[];
  constexpr int SLOTS = (K * 2) / 16;
  constexpr int RB = K * 2;
  int t = threadIdx.x;
  long p0 = (long)blockIdx.x * 128;
  for (int u = t; u < 128 * SLOTS; u += 256) {
    int row = u / SLOTS, slot = u % SLOTS;
    int4 v = *reinterpret_cast<const int4*>(xt + (p0 + row) * K + slot * 8);
    *reinterpret_cast<int4*>(smem + (((u32)(row * RB + slot * 16)) ^ ((row & 7) << 4))) = v;
  }
  __syncthreads();
  int wid = t >> 6, lane = t & 63, l15 = lane & 15, l4 = lane >> 4;
  constexpr int WAVES_M = (N == 64) ? 4 : 2;
  constexpr int MF = (128 / WAVES_M) / 16;
  int wm = (N == 64) ? wid : (wid >> 1);
  int wn = (N == 64) ? 0 : (wid & 1);
  int prow0 = wm * (128 / WAVES_M);
  int ocol0 = wn * 64;
  f32x4 zz = {0.f, 0.f, 0.f, 0.f};
  f32x4 acc[MF][4];
#pragma unroll
  for (int m = 0; m < MF; m++)
#pragma unroll
    for (int n = 0; n < 4; n++) acc[m][n] = zz;
#pragma unroll
  for (int k0 = 0; k0 < K; k0 += 32) {
    bf16x8 a[MF], bw[4];
#pragma unroll
    for (int m = 0; m < MF; m++) {
      int row = prow0 + m * 16 + l15;
      a[m] = ld8(smem + (((u32)(row * RB + (k0 + l4 * 8) * 2)) ^ ((row & 7) << 4)));
    }
#pragma unroll
    for (int n = 0; n < 4; n++) {
      int o = ocol0 + n * 16 + l15;
      bw[n] = ld8(w + (long)o * wstride + k0 + l4 * 8);
    }
#pragma unroll
    for (int m = 0; m < MF; m++)
#pragma unroll
      for (int n = 0; n < 4; n++) acc[m][n] = MFMA16(a[m], bw[n], acc[m][n]);
  }
  if constexpr (!NCHW_OUT) {
#pragma unroll
    for (int m = 0; m < MF; m++)
#pragma unroll
      for (int n = 0; n < 4; n++) {
        int o = ocol0 + n * 16 + l15;
        float bb = bias[o];
#pragma unroll
        for (int r = 0; r < 4; r++) {
          long p = p0 + prow0 + m * 16 + l4 * 4 + r;
          float v = acc[m][n][r] + bb;
          if (RELU) v = fmaxf(v, 0.f);
          out[p * N + o] = f2b(v);
        }
      }
  } else {
    __syncthreads();
    u16* tb = reinterpret_cast<u16*>(smem) + wid * (64 * 66);
#pragma unroll
    for (int m = 0; m < MF; m++)
#pragma unroll
      for (int n = 0; n < 4; n++) {
        float bb = bias[ocol0 + n * 16 + l15];
#pragma unroll
        for (int r = 0; r < 4; r++) {
          int pl = m * 16 + l4 * 4 + r;
          float v = acc[m][n][r] + bb;
          if (RELU) v = fmaxf(v, 0.f);
          tb[(n * 16 + l15) * 66 + pl] = f2b(v);
        }
      }
    __syncthreads();
    int bq = (int)(p0 / HW);
    int rem = (int)(p0 % HW);
    int hq = rem / Ww, wq0 = rem % Ww;
    for (int o = 0; o < 64; o++) {
      out[((long)(bq * 128 + ocol0 + o)) * HW + hq * Ww + wq0 + prow0 + lane] = tb[o * 66 + lane];
    }
  }
}

// ---------------- fused Q/K/V embedding GEMMs (one launch, blockIdx.y selects branch)
__global__ __launch_bounds__(256) void k_emb3(const u16* __restrict__ leftT, const u16* __restrict__ rightT,
                                              const u16* __restrict__ gw, const float* __restrict__ gbias,
                                              u16* __restrict__ QT, u16* __restrict__ KT, u16* __restrict__ VrT) {
  extern __shared__ __align__(16) char smem[];
  int br = blockIdx.y;
  const u16* xt = (br == 0) ? leftT : rightT;
  const u16* w = gw + ((br == 0) ? EMB_L : (br == 1) ? EMB_R : EMB_RV);
  const float* bias = gbias + ((br == 0) ? B_EMBL : (br == 1) ? B_EMBR : B_EMBRV);
  u16* out = (br == 0) ? QT : (br == 1) ? KT : VrT;
  int t = threadIdx.x;
  long p0 = (long)blockIdx.x * 128;
  for (int u = t; u < 2048; u += 256) {
    int row = u >> 4, slot = u & 15;
    int4 v = *reinterpret_cast<const int4*>(xt + (p0 + row) * 128 + slot * 8);
    *reinterpret_cast<int4*>(smem + (((u32)(row * 256 + slot * 16)) ^ ((row & 7) << 4))) = v;
  }
  __syncthreads();
  int wid = t >> 6, lane = t & 63, l15 = lane & 15, l4 = lane >> 4;
  int prow0 = wid * 32;
  f32x4 zz = {0.f, 0.f, 0.f, 0.f};
  f32x4 acc[2][4];
#pragma unroll
  for (int m = 0; m < 2; m++)
#pragma unroll
    for (int n = 0; n < 4; n++) acc[m][n] = zz;
#pragma unroll
  for (int k0 = 0; k0 < 128; k0 += 32) {
    bf16x8 a[2], bw[4];
#pragma unroll
    for (int m = 0; m < 2; m++) {
      int row = prow0 + m * 16 + l15;
      a[m] = ld8(smem + (((u32)(row * 256 + (k0 + l4 * 8) * 2)) ^ ((row & 7) << 4)));
    }
#pragma unroll
    for (int n = 0; n < 4; n++) {
      int o = n * 16 + l15;
      bw[n] = ld8(w + (long)o * 128 + k0 + l4 * 8);
    }
#pragma unroll
    for (int m = 0; m < 2; m++)
#pragma unroll
      for (int n = 0; n < 4; n++) acc[m][n] = MFMA16(a[m], bw[n], acc[m][n]);
  }
#pragma unroll
  for (int m = 0; m < 2; m++)
#pragma unroll
    for (int n = 0; n < 4; n++) {
      int o = n * 16 + l15;
      float bb = bias[o];
#pragma unroll
      for (int r = 0; r < 4; r++) {
        long p = p0 + prow0 + m * 16 + l4 * 4 + r;
        out[p * 64 + o] = f2b(acc[m][n][r] + bb);
      }
    }
}

// ---------------- head: relu(leftT @ Wh[:,:128]^T + rightT @ Wh[:,128:]^T + b), NHWC out
// out may alias rt (in-place safe: each block reads/writes only its own rows).
__global__ __launch_bounds__(256) void k_head(const u16* lt, const u16* rt,
                                              const u16* __restrict__ wh, const float* __restrict__ bh,
                                              u16* out) {
  extern __shared__ __align__(16) char smem[];
  int t = threadIdx.x;
  long p0 = (long)blockIdx.x * 128;
  for (int u = t; u < 2048; u += 256) {
    int row = u >> 4, slot = u & 15;
    u32 db = ((u32)(row * 256 + slot * 16)) ^ ((row & 7) << 4);
    *reinterpret_cast<int4*>(smem + db) = *reinterpret_cast<const int4*>(lt + (p0 + row) * 128 + slot * 8);
    *reinterpret_cast<int4*>(smem + 32768 + db) = *reinterpret_cast<const int4*>(rt + (p0 + row) * 128 + slot * 8);
  }
  __syncthreads();
  int wid = t >> 6, lane = t & 63, l15 = lane & 15, l4 = lane >> 4;
  int prow0 = (wid >> 1) * 64, ocol0 = (wid & 1) * 64;
  f32x4 zz = {0.f, 0.f, 0.f, 0.f};
  f32x4 acc[4][4];
#pragma unroll
  for (int m = 0; m < 4; m++)
#pragma unroll
    for (int n = 0; n < 4; n++) acc[m][n] = zz;
#pragma unroll
  for (int kk = 0; kk < 8; kk++) {
    int k0 = kk * 32;
    const char* sb = smem + ((kk >= 4) ? 32768 : 0);
    int kl = k0 & 127;
    bf16x8 a[4], bw[4];
#pragma unroll
    for (int m = 0; m < 4; m++) {
      int row = prow0 + m * 16 + l15;
      a[m] = ld8(sb + (((u32)(row * 256 + (kl + l4 * 8) * 2)) ^ ((row & 7) << 4)));
    }
#pragma unroll
    for (int n = 0; n < 4; n++) {
      int o = ocol0 + n * 16 + l15;
      bw[n] = ld8(wh + o * 256 + k0 + l4 * 8);
    }
#pragma unroll
    for (int m = 0; m < 4; m++)
#pragma unroll
      for (int n = 0; n < 4; n++) acc[m][n] = MFMA16(a[m], bw[n], acc[m][n]);
  }
  __syncthreads();
#pragma unroll
  for (int m = 0; m < 4; m++)
#pragma unroll
    for (int n = 0; n < 4; n++) {
      int o = ocol0 + n * 16 + l15;
      float bb = bh[o];
#pragma unroll
      for (int r = 0; r < 4; r++) {
        long p = p0 + prow0 + m * 16 + l4 * 4 + r;
        float v = fmaxf(acc[m][n][r] + bb, 0.f);
        out[p * 128 + o] = f2b(v);
      }
    }
}

// ---------------- windowed cross-attention
__global__ __launch_bounds__(256) void k_attn(const u16* __restrict__ qt, const u16* __restrict__ kt,
                                              const u16* __restrict__ vt, u16* __restrict__ outT) {
  extern __shared__ __align__(16) char smem[];
  int n = blockIdx.x, h = blockIdx.y, b = blockIdx.z;
  long rb = ((long)(b * Hh + h)) * Ww + n * 128;
  int t = threadIdx.x;
  for (int u = t; u < 1024; u += 256) {
    int row = u >> 3, slot = u & 7;
    u32 db = ((u32)(row * 128 + slot * 16)) ^ ((row & 7) << 4);
    *reinterpret_cast<int4*>(smem + db) = *reinterpret_cast<const int4*>(qt + (rb + row) * 64 + slot * 8);
    *reinterpret_cast<int4*>(smem + 16384 + db) = *reinterpret_cast<const int4*>(kt + (rb + row) * 64 + slot * 8);
  }
  __syncthreads();
  int wid = t >> 6, lane = t & 63, l15 = lane & 15, l4 = lane >> 4;
  int q0 = wid * 32;
  f32x4 zz = {0.f, 0.f, 0.f, 0.f};
  f32x4 sc[2][8];
#pragma unroll
  for (int m = 0; m < 2; m++)
#pragma unroll
    for (int nf = 0; nf < 8; nf++) sc[m][nf] = zz;
#pragma unroll
  for (int k0 = 0; k0 < 64; k0 += 32) {
    bf16x8 aq[2], bk[8];
#pragma unroll
    for (int m = 0; m < 2; m++) {
      int row = q0 + m * 16 + l15;
      aq[m] = ld8(smem + (((u32)(row * 128 + (k0 + l4 * 8) * 2)) ^ ((row & 7) << 4)));
    }
#pragma unroll
    for (int nf = 0; nf < 8; nf++) {
      int row = nf * 16 + l15;
      bk[nf] = ld8(smem + 16384 + (((u32)(row * 128 + (k0 + l4 * 8) * 2)) ^ ((row & 7) << 4)));
    }
#pragma unroll
    for (int m = 0; m < 2; m++)
#pragma unroll
      for (int nf = 0; nf < 8; nf++) sc[m][nf] = MFMA16(aq[m], bk[nf], sc[m][nf]);
  }
  float rsum[2][4];
#pragma unroll
  for (int m = 0; m < 2; m++) {
#pragma unroll
    for (int r = 0; r < 4; r++) {
      float mx = -3.0e38f;
#pragma unroll
      for (int nf = 0; nf < 8; nf++) mx = fmaxf(mx, sc[m][nf][r]);
      mx = fmaxf(mx, __shfl_xor(mx, 1));
      mx = fmaxf(mx, __shfl_xor(mx, 2));
      mx = fmaxf(mx, __shfl_xor(mx, 4));
      mx = fmaxf(mx, __shfl_xor(mx, 8));
      int ql = q0 + m * 16 + l4 * 4 + r;
      float ssum = 0.f;
#pragma unroll
      for (int nf = 0; nf < 8; nf++) {
        float e = __expf(sc[m][nf][r] - mx);
        ssum += e;
        int k = nf * 16 + l15;
        *reinterpret_cast<u16*>(smem + 32768 + (((u32)(ql * 256 + k * 2)) ^ ((ql & 7) << 4))) = f2b(e);
      }
      ssum += __shfl_xor(ssum, 1);
      ssum += __shfl_xor(ssum, 2);
      ssum += __shfl_xor(ssum, 4);
      ssum += __shfl_xor(ssum, 8);
      rsum[m][r] = ssum;
    }
  }
  __syncthreads();
  for (int u = t; u < 8192; u += 256) {
    int k = u >> 6, c = u & 63;
    u16 v = vt[(rb + k) * 64 + c];
    *reinterpret_cast<u16*>(smem + (((u32)(c * 256 + k * 2)) ^ ((c & 7) << 4))) = v;
  }
  __syncthreads();
  f32x4 ov[2][4];
#pragma unroll
  for (int m = 0; m < 2; m++)
#pragma unroll
    for (int nf = 0; nf < 4; nf++) ov[m][nf] = zz;
#pragma unroll
  for (int k0 = 0; k0 < 128; k0 += 32) {
    bf16x8 ap[2], bv[4];
#pragma unroll
    for (int m = 0; m < 2; m++) {
      int row = q0 + m * 16 + l15;
      ap[m] = ld8(smem + 32768 + (((u32)(row * 256 + (k0 + l4 * 8) * 2)) ^ ((row & 7) << 4)));
    }
#pragma unroll
    for (int nf = 0; nf < 4; nf++) {
      int c = nf * 16 + l15;
      bv[nf] = ld8(smem + (((u32)(c * 256 + (k0 + l4 * 8) * 2)) ^ ((c & 7) << 4)));
    }
#pragma unroll
    for (int m = 0; m < 2; m++)
#pragma unroll
      for (int nf = 0; nf < 4; nf++) ov[m][nf] = MFMA16(ap[m], bv[nf], ov[m][nf]);
  }
#pragma unroll
  for (int m = 0; m < 2; m++)
#pragma unroll
    for (int nf = 0; nf < 4; nf++)
#pragma unroll
      for (int r = 0; r < 4; r++) {
        int q = q0 + m * 16 + l4 * 4 + r;
        int c = nf * 16 + l15;
        outT[(rb + q) * 64 + c] = f2b(ov[m][nf][r] / rsum[m][r]);
      }
}

// ---------------- conv1x9 (round-6 proven structure): x-tile LDS-resident; K=64 weight stages
// via global_load_lds with inverse-swizzled SOURCE + swizzled READ; 32 MFMA per barrier.
template<bool RELU, bool HASRES, bool NCHW_OUT>
__global__ __launch_bounds__(256) void k_conv1x9(const u16* __restrict__ xin, const u16* __restrict__ wp9,
                                                 const float* __restrict__ bias, const u16* __restrict__ res,
                                                 u16* __restrict__ out) {
  __shared__ __align__(16) char xs[34816];   // 136 rows x 256B, XOR-swizzled
  __shared__ __align__(16) char wbuf[32768]; // 2 x 16KB; each [128 o][128B] (K=64), slot-involution
  int w0 = blockIdx.x * 128;
  int h = blockIdx.y, b = blockIdx.z;
  long rowg = ((long)(b * Hh + h)) * Ww;
  int t = threadIdx.x;
  int wid = t >> 6;
  // stage(s): s=0..17, tap=s>>1, khalf=s&1. Physical slot sl holds logical slot sl^(o&7).
  auto stage = [&](int s) {
    int tap = s >> 1, khalf = s & 1;
    const u16* base = wp9 + tap * 16384 + khalf * 64;
#pragma unroll
    for (int j = 0; j < 4; j++) {
      int fidx = j * 256 + t;          // 16B unit index, 0..1023
      int row = fidx >> 3;             // o
      int sl = fidx & 7;               // physical slot
      int l = sl ^ (row & 7);          // logical slot (involution)
      gload16(base + row * 128 + l * 8, wbuf + (s & 1) * 16384 + j * 4096 + wid * 1024);
    }
  };
  // x-tile staging (once)
  for (int u = t; u < 2176; u += 256) {
    int row = u >> 4, slot = u & 15;
    int wg = w0 - 4 + row;
    int4 v{0, 0, 0, 0};
    if (wg >= 0 && wg < Ww) v = *reinterpret_cast<const int4*>(xin + (rowg + wg) * 128 + slot * 8);
    *reinterpret_cast<int4*>(xs + (((u32)(row * 256 + slot * 16)) ^ ((row & 7) << 4))) = v;
  }
  stage(0);
  __syncthreads();
  int lane = t & 63, l15 = lane & 15, l4 = lane >> 4;
  int p0w = (wid >> 1) * 64, o0w = (wid & 1) * 64;
  f32x4 zz = {0.f, 0.f, 0.f, 0.f};
  f32x4 acc[4][4];
#pragma unroll
  for (int m = 0; m < 4; m++)
#pragma unroll
    for (int n = 0; n < 4; n++) acc[m][n] = zz;
#pragma unroll 1
  for (int s = 0; s < 18; s++) {
    if (s < 17) stage(s + 1);
    int tap = s >> 1, khalf = s & 1;
    const char* wb = wbuf + (s & 1) * 16384;
#pragma unroll
    for (int kc = 0; kc < 2; kc++) {
      bf16x8 a[4], bw[4];
#pragma unroll
      for (int n = 0; n < 4; n++) {
        int o = o0w + n * 16 + l15;
        int l = kc * 4 + l4;                       // logical slot
        bw[n] = ld8(wb + o * 128 + (l ^ (o & 7)) * 16);
      }
#pragma unroll
      for (int m = 0; m < 4; m++) {
        int row = p0w + m * 16 + l15 + tap;
        a[m] = ld8(xs + (((u32)(row * 256 + khalf * 128 + kc * 64 + l4 * 16)) ^ ((row & 7) << 4)));
      }
#pragma unroll
      for (int m = 0; m < 4; m++)
#pragma unroll
        for (int n = 0; n < 4; n++) acc[m][n] = MFMA16(a[m], bw[n], acc[m][n]);
    }
    __syncthreads();
  }
  float bb[4];
#pragma unroll
  for (int n = 0; n < 4; n++) bb[n] = bias[o0w + n * 16 + l15];
  if constexpr (!NCHW_OUT) {
#pragma unroll
    for (int m = 0; m < 4; m++)
#pragma unroll
      for (int n = 0; n < 4; n++) {
        int o = o0w + n * 16 + l15;
#pragma unroll
        for (int r = 0; r < 4; r++) {
          int p = w0 + p0w + m * 16 + l4 * 4 + r;
          float v = acc[m][n][r] + bb[n];
          if (RELU) v = fmaxf(v, 0.f);
          if (HASRES) v += b2f(res[(rowg + p) * 128 + o]);
          out[(rowg + p) * 128 + o] = f2b(v);
        }
      }
  } else {
    u16* tb = reinterpret_cast<u16*>(xs) + wid * (64 * 66);
#pragma unroll
    for (int m = 0; m < 4; m++)
#pragma unroll
      for (int n = 0; n < 4; n++) {
        int o = o0w + n * 16 + l15;
#pragma unroll
        for (int r = 0; r < 4; r++) {
          int pl = m * 16 + l4 * 4 + r;
          int p = w0 + p0w + pl;
          float v = acc[m][n][r] + bb[n];
          if (RELU) v = fmaxf(v, 0.f);
          if (HASRES) v += b2f(res[(rowg + p) * 128 + o]);
          tb[(n * 16 + l15) * 66 + pl] = f2b(v);
        }
      }
    __syncthreads();
    for (int o = 0; o < 64; o++) {
      out[((long)(b * 128 + o0w + o)) * HW + h * Ww + w0 + p0w + lane] = tb[o * 66 + lane];
    }
  }
}

// ---------------- pools: ts 0/1 reduce transpose partials; ts 2/3 scan lfw/mixed (bf16 NCHW)
__global__ __launch_bounds__(256) void k_pool(const u16* __restrict__ lfw, const u16* __restrict__ mixed) {
  int c = blockIdx.x, b = blockIdx.y, ts = blockIdx.z;
  float s = 0.f;
  if (ts < 2) {
    const float* pp = g_ppart + ((ts * 2 + b) * 128 + c) * 1024;
    for (int i = threadIdx.x; i < 1024; i += 256) s += pp[i];
  } else {
    long base = ((long)(b * 128 + c)) * HW;
    const u16* pu = (ts == 2) ? lfw + base : mixed + base;
    for (int i = threadIdx.x * 8; i < HW; i += 2048) {
      union { int4 v; u16 u[8]; } x;
      x.v = *reinterpret_cast<const int4*>(pu + i);
#pragma unroll
      for (int j = 0; j < 8; j++) s += b2f(x.u[j]);
    }
  }
#pragma unroll
  for (int m = 1; m < 64; m <<= 1) s += __shfl_xor(s, m);
  __shared__ float red[4];
  if ((threadIdx.x & 63) == 0) red[threadIdx.x >> 6] = s;
  __syncthreads();
  if (threadIdx.x == 0)
    g_pools[(ts * 2 + b) * 128 + c] = (red[0] + red[1] + red[2] + red[3]) * (1.f / HW);
}

// ---------------- SKN gate MLP + branch softmax (tiny)
__global__ void k_gate() {
  __shared__ float sv[128], zv[32];
  int b = blockIdx.x, s = blockIdx.y;
  int t = threadIdx.x;
  sv[t] = g_pools[(s * 2 + b) * 128 + t] + g_pools[(4 + b) * 128 + t] + g_pools[(6 + b) * 128 + t];
  __syncthreads();
  const float* fc1 = g_fc + (s ? FC1B : FC1A);
  const float* fc2 = g_fc + (s ? FC2B : FC2A);
  if (t < 32) {
    float z = 0.f;
    for (int c = 0; c < 128; c++) z += fc1[t * 128 + c] * sv[c];
    zv[t] = (z > 0.f) ? z : 0.01f * z;
  }
  __syncthreads();
  float ab[3];
#pragma unroll
  for (int i = 0; i < 3; i++) {
    float a = 0.f;
    for (int j = 0; j < 32; j++) a += fc2[(i * 128 + t) * 32 + j] * zv[j];
    ab[i] = a;
  }
  float mx = fmaxf(ab[0], fmaxf(ab[1], ab[2]));
  float e0 = __expf(ab[0] - mx), e1 = __expf(ab[1] - mx), e2 = __expf(ab[2] - mx);
  float inv = 1.f / (e0 + e1 + e2);
  g_gates[((s * 2 + b) * 3 + 0) * 128 + t] = e0 * inv;
  g_gates[((s * 2 + b) * 3 + 1) * 128 + t] = e1 * inv;
  g_gates[((s * 2 + b) * 3 + 2) * 128 + t] = e2 * inv;
}

// ---------------- final weighted sums -> d_out (flag dtype)
__global__ __launch_bounds__(256) void k_skn_out(const void* left, const void* right,
                                                 const u16* __restrict__ lfw, const u16* __restrict__ mixed,
                                                 void* doutv) {
  int chunk = blockIdx.x, c = blockIdx.y, b = blockIdx.z;
  int f = g_flag;
  const float* g1 = g_gates + (b * 3) * 128 + c;
  const float* g2 = g_gates + ((2 + b) * 3) * 128 + c;
  float a10 = g1[0], a11 = g1[128], a12 = g1[256];
  float a20 = g2[0], a21 = g2[128], a22 = g2[256];
  long off = ((long)(b * 128 + c)) * HW + chunk * 2048 + threadIdx.x * 8;
  float xl[8], xr[8];
  if (f) {
    const float* L = (const float*)left + off;
    const float* R = (const float*)right + off;
    float4 a0 = *reinterpret_cast<const float4*>(L);
    float4 a1 = *reinterpret_cast<const float4*>(L + 4);
    float4 r0 = *reinterpret_cast<const float4*>(R);
    float4 r1 = *reinterpret_cast<const float4*>(R + 4);
    xl[0]=a0.x; xl[1]=a0.y; xl[2]=a0.z; xl[3]=a0.w; xl[4]=a1.x; xl[5]=a1.y; xl[6]=a1.z; xl[7]=a1.w;
    xr[0]=r0.x; xr[1]=r0.y; xr[2]=r0.z; xr[3]=r0.w; xr[4]=r1.x; xr[5]=r1.y; xr[6]=r1.z; xr[7]=r1.w;
  } else {
    union { int4 v; u16 u[8]; } a, r;
    a.v = *reinterpret_cast<const int4*>((const u16*)left + off);
    r.v = *reinterpret_cast<const int4*>((const u16*)right + off);
#pragma unroll
    for (int j = 0; j < 8; j++) { xl[j] = b2f(a.u[j]); xr[j] = b2f(r.u[j]); }
  }
  union { int4 v; u16 u[8]; } vw, vm;
  vw.v = *reinterpret_cast<const int4*>(lfw + off);
  vm.v = *reinterpret_cast<const int4*>(mixed + off);
  float ol[8], orr[8];
#pragma unroll
  for (int j = 0; j < 8; j++) {
    float fw = b2f(vw.u[j]), fm = b2f(vm.u[j]);
    ol[j] = a10 * xl[j] + a11 * fw + a12 * fm;
    orr[j] = a20 * xr[j] + a21 * fw + a22 * fm;
  }
  if (f) {
    float* fo = (float*)doutv;
    *reinterpret_cast<float4*>(fo + off) = make_float4(ol[0], ol[1], ol[2], ol[3]);
    *reinterpret_cast<float4*>(fo + off + 4) = make_float4(ol[4], ol[5], ol[6], ol[7]);
    *reinterpret_cast<float4*>(fo + FULL + off) = make_float4(orr[0], orr[1], orr[2], orr[3]);
    *reinterpret_cast<float4*>(fo + FULL + off + 4) = make_float4(orr[4], orr[5], orr[6], orr[7]);
  } else {
    u16* bo = (u16*)doutv;
    union { int4 v; u16 u[8]; } o1, o2;
#pragma unroll
    for (int j = 0; j < 8; j++) { o1.u[j] = f2b(ol[j]); o2.u[j] = f2b(orr[j]); }
    *reinterpret_cast<int4*>(bo + off) = o1.v;
    *reinterpret_cast<int4*>(bo + FULL + off) = o2.v;
  }
}

extern "C" void kernel_launch(void* const* d_in, const int* in_sizes, int n_in,
                              void* d_out, int out_size, void* d_ws, size_t ws_size,
                              hipStream_t stream) {
  (void)in_sizes; (void)n_in; (void)out_size; (void)d_ws; (void)ws_size;
  const void* left    = d_in[0];
  const void* right   = d_in[1];

  u16* gbuf = nullptr;
  (void)hipGetSymbolAddress((void**)&gbuf, HIP_SYMBOL(g_buf));
  u16* gw = nullptr;
  (void)hipGetSymbolAddress((void**)&gw, HIP_SYMBOL(g_w));
  float* gbias = nullptr;
  (void)hipGetSymbolAddress((void**)&gbias, HIP_SYMBOL(g_bias));

  // scratch plan (no D2D copies; end-state lfw/mixed in g_buf, d_out free before k_skn_out):
  u16* du = (u16*)d_out;
  u16* leftT   = du;                    // [0, FULL)        dead after k_head
  u16* rA      = du;                    // [0, FULL)        conv ping (after leftT dead)
  u16* rightT  = du + FULL;             // [FULL, 2FULL)    dead after k_head (head emits in-place)
  u16* xG      = du + FULL;             // [FULL, 2FULL)    head output / conv pong
  u16* QT      = gbuf;                  // [0, HALF)        dead after attn
  u16* KT      = gbuf + HALF;           // [HALF, FULL)     dead after attn
  u16* VrT     = gbuf + FULL;           // [FULL, 1.5FULL)  dead after attn
  u16* warpedT = gbuf + FULL + HALF;    // [1.5FULL, 2FULL) dead after out_l
  u16* lfw     = gbuf;                  // [0, FULL)        NCHW, lives to end (QT/KT dead)
  u16* mixed   = gbuf + FULL;           // [FULL, 2FULL)    NCHW, lives to end (VrT/warped dead)

  k_detect<<<dim3(1), dim3(64), 0, stream>>>(left);
  k_pack<<<dim3(3456, 4), dim3(256), 0, stream>>>(
      d_in[14], d_in[16], d_in[2], d_in[4], d_in[8], d_in[10], d_in[12],
      d_in[3], d_in[5], d_in[9], d_in[11], d_in[13], d_in[15], d_in[17],
      d_in[18], d_in[19], d_in[20], d_in[21]);
  k_nchw2nhwc<<<dim3(8, 128, 4), dim3(256), 0, stream>>>(left, right, leftT, rightT);
  k_emb3<<<dim3(1024, 3), dim3(256), 32768, stream>>>(leftT, rightT, gw, gbias, QT, KT, VrT);
  k_head<<<dim3(1024), dim3(256), 65536, stream>>>(leftT, rightT, gw + HEAD, gbias + B_HEAD, xG);  // in-place over rightT
  k_attn<<<dim3(4, 128, 2), dim3(256), 65536, stream>>>(QT, KT, VrT, warpedT);          // QT,KT,VrT dead
  k_gemm1x1<64, 128, true, true><<<dim3(1024), dim3(256), 33792, stream>>>(warpedT, gw + OUTL, gbias + B_OUTL, lfw, 64);
  for (int i = 0; i < 3; i++) {
    k_conv1x9<true, false, false><<<dim3(4, 128, 2), dim3(256), 0, stream>>>(
        xG, gw + BODY + (long)(i * 2 + 0) * 9 * 16384, gbias + B_B1 + i * 128, nullptr, rA);
    if (i < 2)
      k_conv1x9<false, true, false><<<dim3(4, 128, 2), dim3(256), 0, stream>>>(
          rA, gw + BODY + (long)(i * 2 + 1) * 9 * 16384, gbias + B_B2 + i * 128, xG, xG);
    else
      k_conv1x9<false, true, true><<<dim3(4, 128, 2), dim3(256), 0, stream>>>(
          rA, gw + BODY + (long)(i * 2 + 1) * 9 * 16384, gbias + B_B2 + i * 128, xG, mixed);
  }
  k_pool<<<dim3(128, 2, 4), dim3(256), 0, stream>>>(lfw, mixed);
  k_gate<<<dim3(2, 2), dim3(128), 0, stream>>>();
  k_skn_out<<<dim3(32, 128, 2), dim3(256), 0, stream>>>(left, right, lfw, mixed, d_out);
}